// Round 10
// baseline (822097.266 us; speedup 1.0000x reference)
//
#include <hip/hip_runtime.h>
#include <math.h>

// Problem constants
#define B_ROWS 8192
#define S_LEN  512
#define H_DIM  256
#define G3     768          // 3*H
#define P_DIM  96
#define TB     16           // batch rows per block (2 blocks/CU)

typedef __attribute__((ext_vector_type(8))) _Float16 half8;  // 8 f16 (4 VGPRs)
typedef __attribute__((ext_vector_type(4))) float floatx4;   // MFMA C/D frag

__device__ __forceinline__ float sigmoid_fast(float v) {
    return 1.0f / (1.0f + __expf(-v));
}
__device__ __forceinline__ float tanh_fast(float v) {
    return 1.0f - 2.0f / (__expf(2.0f * v) + 1.0f);
}
__device__ __forceinline__ unsigned short f32_f16(float f) {
    _Float16 h = (_Float16)f;                 // RTN
    return __builtin_bit_cast(unsigned short, h);
}
// Involutive 6-bit lane rotation: spreads scatter dest-lanes across bank groups.
__device__ __forceinline__ int rot3(int l) { return ((l << 3) | (l >> 3)) & 63; }

// -------- One-time weight pack: W_hh -> per-lane MFMA B-fragments (hi/lo fp16).
// h in (-1,1) is sent as SINGLE fp16.  W precision policy:
//   k=0..223 (kc=0..6): SINGLE fp16 hi only (kc0-5 streamed, kc6 from LDS)
//   k=224..255 (kc=7, registers): split hi+lo (~2^-22 capture)
// B[k][n] = W_hh[n][k].  16x16x32 B-frag: lane holds B[n=lane&15][k=quad*8+j].
// Tile index = (k>>5)*48 + (j>>4); lane = (j&15) | (((k>>3)&3)<<4); short = k&7.
// Also WoT[k][p] = W_out[p][k]; also zeroes the phase-sync counter.
__global__ void pack_weights(const float* __restrict__ W_hh,
                             const float* __restrict__ W_out,
                             unsigned short* __restrict__ Bh,
                             unsigned short* __restrict__ Bl,
                             float* __restrict__ WoT,
                             unsigned int* __restrict__ ctr) {
    const int j = blockIdx.x;    // gate col 0..767
    const int k = threadIdx.x;   // h idx   0..255
    const float wv = W_hh[j * H_DIM + k];
    const unsigned short hi = f32_f16(wv);
    const float hf = (float)__builtin_bit_cast(_Float16, hi);
    const unsigned short lo = f32_f16(wv - hf);
    const int idx = (((k >> 5) * 48 + (j >> 4)) * 64 +
                     ((j & 15) | (((k >> 3) & 3) << 4))) * 8 + (k & 7);
    Bh[idx] = hi;
    Bl[idx] = lo;
    if (j < P_DIM) WoT[k * P_DIM + j] = W_out[j * H_DIM + k];
    if (j == 0 && k == 0) *ctr = 0u;   // d_ws is re-poisoned every launch
}

// LDS layout (66 KiB per block -> TWO blocks fit per CU's 160 KiB):
//   [0,     16384)  A-fragments (fp16), double-buffered:
//                   buf*8192 + kc*1024 + slot*16 + short*2  (slot = rot3'd)
//   [16384, 18432)  xtile[2][16][16] fp32
//   [18432, 67584)  W cache: 48 tiles x 1 KiB = kc=6 hi
//                   (index T=(gh>>1)*16+w*2+(gh&1))
#define A_OFF   0
#define X_OFF   16384
#define W_OFF   18432
#define LDS_SZ  67584

// Issue 6 streamed hi-tile loads for one kc (stay in flight until MFMA use).
__device__ __forceinline__ void gissue1(half8 (&BH)[6],
                                        const unsigned short* (&pbh)[6],
                                        int kc) {
#pragma unroll
    for (int gh = 0; gh < 6; ++gh)
        BH[gh] = *(const half8*)(pbh[gh] + (size_t)kc * 24576);
}

__device__ __forceinline__ void ahread1(half8& AH, const char* Ac,
                                        int kc, int rl) {
    AH = *(const half8*)(Ac + kc * 1024 + rl * 16);
}

// Single-precision kc block: 6 MFMAs (hi product only).
__device__ __forceinline__ void kcmfma1(floatx4 (&acc)[3][2],
                                        const half8& AH,
                                        const half8 (&BH)[6]) {
#pragma unroll
    for (int gh = 0; gh < 6; ++gh) {
        floatx4& c = acc[gh >> 1][gh & 1];
        c = __builtin_amdgcn_mfma_f32_16x16x32_f16(AH, BH[gh], c, 0, 0, 0);
    }
}

// Split-precision kc block: 12 MFMAs (hi+lo) — used for kc7 (registers).
__device__ __forceinline__ void kcmfma2(floatx4 (&acc)[3][2],
                                        const half8& AH,
                                        const half8 (&BH)[6],
                                        const half8 (&BL)[6]) {
#pragma unroll
    for (int gh = 0; gh < 6; ++gh) {
        floatx4& c = acc[gh >> 1][gh & 1];
        c = __builtin_amdgcn_mfma_f32_16x16x32_f16(AH, BH[gh], c, 0, 0, 0);
        c = __builtin_amdgcn_mfma_f32_16x16x32_f16(AH, BL[gh], c, 0, 0, 0);
    }
}

// Main persistent GRU kernel, round 10: TWO blocks per CU, register-safe.
// Round 8 proved 2 blocks co-reside (Occupancy 47%) but __launch_bounds__
// (512,4) = MIN 4 BLOCKS/CU capped VGPRs at 64 -> catastrophic scratch spill
// (FETCH 13 GB).  (512,2) caps at 128, which rounds 3-9 prove this codegen
// fits WITHOUT spill.  Independent per-block barriers let block B issue
// MFMAs while block A drains its barrier / runs its serial gate phase —
// filling the ~50% no-issue gap measured on the 1-block structure.
// grid = 512 (2 blocks/CU), block = 512 (8 waves).
__global__ __launch_bounds__(512, 2)
void gru_mfma(const float* __restrict__ x,
              const float* __restrict__ W_ih,
              const float* __restrict__ b_ih,
              const float* __restrict__ b_hh,
              const unsigned short* __restrict__ Bh,
              const unsigned short* __restrict__ Bl,
              const float* __restrict__ WoT,   // [256][96]
              const float* __restrict__ b_out,
              float* __restrict__ out,
              unsigned int* __restrict__ ctr) {
    __shared__ __align__(16) char smem[LDS_SZ];

    const int tid  = threadIdx.x;
    const int w    = tid >> 6;     // wave 0..7
    const int lane = tid & 63;
    const int q    = lane >> 4;    // quad
    const int c    = lane & 15;
    const int row0 = blockIdx.x * TB;

    // Per-thread gate params; col = 256*g + 32*w + 16*ht + c
    float wih[3][2], bcc[2][2], bihn[2], bhhn[2];
#pragma unroll
    for (int g = 0; g < 3; ++g)
#pragma unroll
        for (int ht = 0; ht < 2; ++ht) {
            const int col = g * H_DIM + w * 32 + ht * 16 + c;
            wih[g][ht] = W_ih[col];
            if (g < 2) {
                bcc[g][ht] = b_ih[col] + b_hh[col];
            } else {
                bihn[ht] = b_ih[col];
                bhhn[ht] = b_hh[col];
            }
        }

    // Streamed-tile base pointers (per wave/lane), gh = g*2 + ht.
    const unsigned short* pbh[6];
    const unsigned short* pbl[6];
#pragma unroll
    for (int gh = 0; gh < 6; ++gh) {
        const size_t toff = (size_t)((gh >> 1) * 16 + w * 2 + (gh & 1)) * 512 + lane * 8;
        pbh[gh] = Bh + toff;
        pbl[gh] = Bl + toff;
    }

    // Register-resident weight tiles: kc=7 hi+lo.  (48 VGPRs)
    half8 r7h[6], r7l[6];
#pragma unroll
    for (int gh = 0; gh < 6; ++gh) {
        r7h[gh] = *(const half8*)(pbh[gh] + 7 * 24576);
        r7l[gh] = *(const half8*)(pbl[gh] + 7 * 24576);
    }

    // LDS weight cache staging: 48 tiles = kc=6 hi.
    for (int i = tid; i < 48 * 64; i += 512) {
        const int slot = i >> 6, l16 = i & 63;
        const unsigned short* src = Bh + (size_t)(288 + slot) * 512 + l16 * 8;
        *(uint4*)(smem + W_OFF + slot * 1024 + l16 * 16) = *(const uint4*)src;
    }

    // Zero both A-frag buffers (h0 = 0) and stage x for t=0..15.
    for (int i = tid; i < 4096; i += 512) ((int*)(smem + A_OFF))[i] = 0;
    float* xt = (float*)(smem + X_OFF);
    if (tid < 256) {
        const int r = tid >> 4, t2 = tid & 15;
        xt[r * 16 + t2] = x[(size_t)(row0 + r) * S_LEN + t2];
    }
    __syncthreads();

    // h_old in C-frag layout: element (ht,reg) = h[4q+reg][32w+16ht+c]
    float h_own[2][4];
#pragma unroll
    for (int ht = 0; ht < 2; ++ht)
#pragma unroll
        for (int r = 0; r < 4; ++r) h_own[ht][r] = 0.0f;

    const int rl = rot3(lane);

    // Loop-invariant precompute: scatter byte offsets, x row offsets,
    // kc6 LDS tile bases.
    int soff[2][4];                 // [ht][r] -> rot3(d)*16 + (c&7)*2
#pragma unroll
    for (int ht = 0; ht < 2; ++ht)
#pragma unroll
        for (int r = 0; r < 4; ++r) {
            const int d = (q * 4 + r) | ((2 * ht + (c >> 3)) << 4);
            soff[ht][r] = rot3(d) * 16 + (c & 7) * 2;
        }
    int xbase[4];                   // [r] -> (q*4+r)*16
#pragma unroll
    for (int r = 0; r < 4; ++r) xbase[r] = (q * 4 + r) * 16;
    const char* w6base[6];          // kc6 hi tile
#pragma unroll
    for (int gh = 0; gh < 6; ++gh) {
        const int T = (gh >> 1) * 16 + w * 2 + (gh & 1);
        w6base[gh] = smem + W_OFF + T * 1024 + lane * 16;
    }

    // Pipeline buffers (static names only — rule: no runtime indexing).
    half8 b0h[6], b1h[6];
    half8 ahA, ahB;

    // Prologue: kc=0 of step 0 in flight before the loop.
    gissue1(b0h, pbh, 0);

#pragma unroll 1
    for (int t = 0; t < S_LEN; ++t) {
        // Defeat LICM of the (t-invariant) streamed loads.
#pragma unroll
        for (int gh = 0; gh < 6; ++gh)
            asm volatile("" : "+v"(pbh[gh]));

        const int cur = t & 1, nxt = cur ^ 1;
        const char* Ac = smem + A_OFF + cur * 8192;

        ahread1(ahA, Ac, 0, rl);           // A-frag for kc=0
        gissue1(b1h, pbh, 1);              // kc=1 stream in flight

        // x for my 4 rows (LDS broadcast); xidx is wave-uniform per step.
        const int xidx = ((t >> 4) & 1) * 256 + (t & 15);
        float xr[4];
#pragma unroll
        for (int r = 0; r < 4; ++r) xr[r] = xt[xbase[r] + xidx];

        // C frags [gate][ht]; fold x-side pre-activation + bias into init.
        floatx4 acc[3][2];
#pragma unroll
        for (int ht = 0; ht < 2; ++ht)
#pragma unroll
            for (int r = 0; r < 4; ++r) {
                acc[0][ht][r] = fmaf(xr[r], wih[0][ht], bcc[0][ht]);
                acc[1][ht][r] = fmaf(xr[r], wih[1][ht], bcc[1][ht]);
                acc[2][ht][r] = bhhn[ht];
            }

        // ---- Pipelined kc ladder (single-fp16 stream) ----
        ahread1(ahB, Ac, 1, rl);
        kcmfma1(acc, ahA, b0h);                           // kc0
        gissue1(b0h, pbh, 2);
        ahread1(ahA, Ac, 2, rl);
        kcmfma1(acc, ahB, b1h);                           // kc1
        gissue1(b1h, pbh, 3);
        ahread1(ahB, Ac, 3, rl);
        kcmfma1(acc, ahA, b0h);                           // kc2
        gissue1(b0h, pbh, 4);
        ahread1(ahA, Ac, 4, rl);
        kcmfma1(acc, ahB, b1h);                           // kc3
        gissue1(b1h, pbh, 5);
        ahread1(ahB, Ac, 5, rl);
        kcmfma1(acc, ahA, b0h);                           // kc4
        ahread1(ahA, Ac, 6, rl);
        kcmfma1(acc, ahB, b1h);                           // kc5

        // ---- kc6: hi from the LDS cache (single precision) ----
        {
            half8 w6h[6];
#pragma unroll
            for (int gh = 0; gh < 6; ++gh)
                w6h[gh] = *(const half8*)(w6base[gh]);
            ahread1(ahB, Ac, 7, rl);
            kcmfma1(acc, ahA, w6h);                       // kc6
        }

        // Prefetch next step's kc0 while kc7 + gates + barrier run.
        gissue1(b0h, pbh, 0);
        kcmfma2(acc, ahB, r7h, r7l);                      // kc7 (split)

        // Gates + h update (in-register); scatter next A-frag (rot3-swizzled).
        char* Anx = smem + A_OFF + nxt * 8192;
        char* ch  = Anx + w * 1024;                       // chunk kc=w
#pragma unroll
        for (int ht = 0; ht < 2; ++ht)
#pragma unroll
            for (int r = 0; r < 4; ++r) {
                const float rr  = sigmoid_fast(acc[0][ht][r]);
                const float zz  = sigmoid_fast(acc[1][ht][r]);
                const float inn = fmaf(xr[r], wih[2][ht], bihn[ht]);
                const float nn  = tanh_fast(fmaf(rr, acc[2][ht][r], inn));
                const float hv  = (1.0f - zz) * nn + zz * h_own[ht][r];
                h_own[ht][r] = hv;
                *(unsigned short*)(ch + soff[ht][r]) = f32_f16(hv);
            }

        // Re-stage x for the next 16 steps (into the idle x buffer).
        const bool tick = ((t & 15) == 15) && (t != S_LEN - 1);
        if (tick && tid < 256) {
            const int r = tid >> 4, t2 = tid & 15;
            xt[((((t + 1) >> 4) & 1) * 16 + r) * 16 + t2] =
                x[(size_t)(row0 + r) * S_LEN + (t + 1) + t2];
        }
        __syncthreads();   // single barrier: next A-frags + x tile visible

        // Phase-alignment heartbeat every 16 steps (512 blocks): keeps the
        // weight streams coarsely in phase so the per-XCD L2 working set
        // stays hot.  Bounded spin, no data dependency, no fences.
        if (tick) {
            if (tid == 0) {
                const unsigned int tgt = 512u * (unsigned)((t >> 4) + 1);
                atomicAdd(ctr, 1u);
                for (int spin = 0; spin < (1 << 17); ++spin) {
                    if (__hip_atomic_load(ctr, __ATOMIC_RELAXED,
                                          __HIP_MEMORY_SCOPE_AGENT) >= tgt) break;
                    __builtin_amdgcn_s_sleep(4);
                }
            }
            __syncthreads();
        }
    }

    // -------- Epilogue: dump final h (fp32, from registers) and project.
    float* hfin = (float*)(smem);   // reuse A region: [16][256] = 16 KiB
#pragma unroll
    for (int ht = 0; ht < 2; ++ht)
#pragma unroll
        for (int r = 0; r < 4; ++r) {
            const int m = q * 4 + r;
            const int k = w * 32 + ht * 16 + c;
            hfin[m * H_DIM + k] = h_own[ht][r];
        }
    __syncthreads();

    if (tid < 256) {
        const int cid   = tid & 63;
        const int rid   = tid >> 6;     // 0..3
        const int myrow = rid * 4;      // 4 rows each -> 16 rows
        const int pA    = cid;
        const int pB    = 64 + cid;
        const bool hasB = (cid < 32);
        float accA[4], accB[4];
#pragma unroll
        for (int rr = 0; rr < 4; ++rr) { accA[rr] = 0.0f; accB[rr] = 0.0f; }

        for (int k = 0; k < H_DIM; k += 4) {
            float4 hv[4];
#pragma unroll
            for (int rr = 0; rr < 4; ++rr)
                hv[rr] = *(const float4*)&hfin[(myrow + rr) * H_DIM + k];
            float wA[4], wB[4];
#pragma unroll
            for (int kk = 0; kk < 4; ++kk) {
                wA[kk] = WoT[(size_t)(k + kk) * P_DIM + pA];
                wB[kk] = hasB ? WoT[(size_t)(k + kk) * P_DIM + pB] : 0.0f;
            }
#pragma unroll
            for (int kk = 0; kk < 4; ++kk)
#pragma unroll
                for (int rr = 0; rr < 4; ++rr) {
                    const float hvv = (&hv[rr].x)[kk];
                    accA[rr] = fmaf(hvv, wA[kk], accA[rr]);
                    accB[rr] = fmaf(hvv, wB[kk], accB[rr]);
                }
        }
        const float boA = b_out[pA];
        const float boB = hasB ? b_out[pB] : 0.0f;
#pragma unroll
        for (int rr = 0; rr < 4; ++rr) {
            const size_t orow = (size_t)(row0 + myrow + rr) * P_DIM;
            out[orow + pA] = accA[rr] + boA;
            if (hasB) out[orow + pB] = accB[rr] + boB;
        }
    }
}

// -------- fp32 fallback — used only if ws_size is too small.
#define FTB 32
__global__ __launch_bounds__(256, 1)
void gru_fallback(const float* __restrict__ x,
                  const float* __restrict__ W_ih,
                  const float* __restrict__ Whh,
                  const float* __restrict__ b_ih,
                  const float* __restrict__ b_hh,
                  const float* __restrict__ Wout,
                  const float* __restrict__ b_out,
                  float* __restrict__ out) {
    __shared__ float hbuf[2][FTB][H_DIM];

    const int tid   = threadIdx.x;
    const int cid   = tid & 63;
    const int rid   = tid >> 6;
    const int row0  = blockIdx.x * FTB;
    const int myrow = rid * 8;
    const int c0    = cid * 4;

    float wih[3][4], bc[2][4], bihn[4], bhhn[4];
#pragma unroll
    for (int cc = 0; cc < 4; ++cc) {
        const int j = c0 + cc;
        wih[0][cc] = W_ih[j];
        wih[1][cc] = W_ih[H_DIM + j];
        wih[2][cc] = W_ih[2 * H_DIM + j];
        bc[0][cc]  = b_ih[j] + b_hh[j];
        bc[1][cc]  = b_ih[H_DIM + j] + b_hh[H_DIM + j];
        bihn[cc]   = b_ih[2 * H_DIM + j];
        bhhn[cc]   = b_hh[2 * H_DIM + j];
    }
    for (int i = tid; i < FTB * H_DIM; i += 256) (&hbuf[0][0][0])[i] = 0.0f;
    float h_own[8][4];
#pragma unroll
    for (int rr = 0; rr < 8; ++rr)
#pragma unroll
        for (int cc = 0; cc < 4; ++cc) h_own[rr][cc] = 0.0f;
    __syncthreads();

    int p = 0;
    for (int t = 0; t < S_LEN; ++t) {
        float xv[8];
#pragma unroll
        for (int rr = 0; rr < 8; ++rr)
            xv[rr] = x[(size_t)(row0 + myrow + rr) * S_LEN + t];

        float acc[3][8][4];
#pragma unroll
        for (int rr = 0; rr < 8; ++rr)
#pragma unroll
            for (int cc = 0; cc < 4; ++cc) {
                acc[0][rr][cc] = fmaf(xv[rr], wih[0][cc], bc[0][cc]);
                acc[1][rr][cc] = fmaf(xv[rr], wih[1][cc], bc[1][cc]);
                acc[2][rr][cc] = bhhn[cc];
            }
        const float* hb = &hbuf[p][0][0];
        for (int k = 0; k < H_DIM; k += 4) {
            float4 hv[8];
#pragma unroll
            for (int rr = 0; rr < 8; ++rr)
                hv[rr] = *(const float4*)(hb + (myrow + rr) * H_DIM + k);
#pragma unroll
            for (int g = 0; g < 3; ++g)
#pragma unroll
                for (int kk = 0; kk < 4; ++kk) {
                    float wrow[4];
#pragma unroll
                    for (int cc = 0; cc < 4; ++cc)
                        wrow[cc] = Whh[(size_t)(g * H_DIM + c0 + cc) * H_DIM + k + kk];
#pragma unroll
                    for (int rr = 0; rr < 8; ++rr) {
                        const float hvv = (&hv[rr].x)[kk];
#pragma unroll
                        for (int cc = 0; cc < 4; ++cc)
                            acc[g][rr][cc] = fmaf(hvv, wrow[cc], acc[g][rr][cc]);
                    }
                }
        }
#pragma unroll
        for (int rr = 0; rr < 8; ++rr) {
            float4 hnew;
#pragma unroll
            for (int cc = 0; cc < 4; ++cc) {
                const float r_  = sigmoid_fast(acc[0][rr][cc]);
                const float z_  = sigmoid_fast(acc[1][rr][cc]);
                const float i_n = fmaf(xv[rr], wih[2][cc], bihn[cc]);
                const float n_  = tanh_fast(fmaf(r_, acc[2][rr][cc], i_n));
                const float hv2 = (1.0f - z_) * n_ + z_ * h_own[rr][cc];
                h_own[rr][cc] = hv2;
                (&hnew.x)[cc] = hv2;
            }
            *(float4*)&hbuf[1 - p][myrow + rr][c0] = hnew;
        }
        __syncthreads();
        p ^= 1;
    }

    const int  pA   = cid;
    const int  pB   = 64 + cid;
    const bool hasB = (cid < 32);
    float accA[8], accB[8];
#pragma unroll
    for (int rr = 0; rr < 8; ++rr) { accA[rr] = 0.0f; accB[rr] = 0.0f; }
    for (int k = 0; k < H_DIM; k += 4) {
        float4 hv[8];
#pragma unroll
        for (int rr = 0; rr < 8; ++rr)
            hv[rr] = *(const float4*)&hbuf[p][myrow + rr][k];
        float wA[4], wB[4];
#pragma unroll
        for (int kk = 0; kk < 4; ++kk) {
            wA[kk] = Wout[(size_t)pA * H_DIM + k + kk];
            wB[kk] = hasB ? Wout[(size_t)pB * H_DIM + k + kk] : 0.0f;
        }
#pragma unroll
        for (int kk = 0; kk < 4; ++kk)
#pragma unroll
            for (int rr = 0; rr < 8; ++rr) {
                const float hvv = (&hv[rr].x)[kk];
                accA[rr] = fmaf(hvv, wA[kk], accA[rr]);
                accB[rr] = fmaf(hvv, wB[kk], accB[rr]);
            }
    }
    const float boA = b_out[pA];
    const float boB = hasB ? b_out[pB] : 0.0f;
#pragma unroll
    for (int rr = 0; rr < 8; ++rr) {
        const size_t orow = (size_t)(row0 + myrow + rr) * P_DIM;
        out[orow + pA] = accA[rr] + boA;
        if (hasB) out[orow + pB] = accB[rr] + boB;
    }
}

extern "C" void kernel_launch(void* const* d_in, const int* in_sizes, int n_in,
                              void* d_out, int out_size, void* d_ws, size_t ws_size,
                              hipStream_t stream) {
    const float* x     = (const float*)d_in[0];
    const float* W_ih  = (const float*)d_in[1];
    const float* W_hh  = (const float*)d_in[2];
    const float* b_ih  = (const float*)d_in[3];
    const float* b_hh  = (const float*)d_in[4];
    const float* W_out = (const float*)d_in[5];
    const float* b_out = (const float*)d_in[6];
    float* out = (float*)d_out;

    const size_t bpack_elems = 8 * 48 * 64 * 8;          // 196608 f16 per matrix
    const size_t wot_elems   = (size_t)H_DIM * P_DIM;    // 24576 fp32
    const size_t ctr_off = bpack_elems * 2 * sizeof(unsigned short) * 2 +
                           wot_elems * sizeof(float);    // 1671168 B (16-aligned)
    const size_t need = ctr_off + sizeof(unsigned int);

    if (ws_size >= need) {
        unsigned short* Bh = (unsigned short*)d_ws;
        unsigned short* Bl = Bh + bpack_elems * 2;
        float* WoT = (float*)(Bl + bpack_elems * 2);
        unsigned int* ctr = (unsigned int*)((char*)d_ws + ctr_off);
        pack_weights<<<G3, H_DIM, 0, stream>>>(W_hh, W_out, Bh, Bl, WoT, ctr);
        gru_mfma<<<B_ROWS / TB, 512, 0, stream>>>(x, W_ih, b_ih, b_hh,
                                                  Bh, Bl, WoT, b_out, out, ctr);
    } else {
        gru_fallback<<<B_ROWS / 32, 256, 0, stream>>>(x, W_ih, W_hh, b_ih, b_hh,
                                                      W_out, b_out, out);
    }
}

// Round 11
// 3482.681 us; speedup vs baseline: 236.0530x; 236.0530x over previous
//
#include <hip/hip_runtime.h>
#include <math.h>

// Problem constants
#define B_ROWS 8192
#define S_LEN  512
#define H_DIM  256
#define G3     768          // 3*H
#define P_DIM  96
#define TB     32           // batch rows per block

typedef __attribute__((ext_vector_type(8))) _Float16 half8;  // 8 f16 (4 VGPRs)
typedef __attribute__((ext_vector_type(4))) float floatx4;   // MFMA C/D frag

__device__ __forceinline__ float sigmoid_fast(float v) {
    return 1.0f / (1.0f + __expf(-v));
}
__device__ __forceinline__ float tanh_fast(float v) {
    return 1.0f - 2.0f / (__expf(2.0f * v) + 1.0f);
}
__device__ __forceinline__ unsigned short f32_f16(float f) {
    _Float16 h = (_Float16)f;                 // RTN
    return __builtin_bit_cast(unsigned short, h);
}
// Involutive 6-bit lane rotation: spreads scatter dest-lanes across bank groups.
__device__ __forceinline__ int rot3(int l) { return ((l << 3) | (l >> 3)) & 63; }

// -------- One-time weight pack: W_hh -> per-lane MFMA B-fragments (hi/lo fp16).
// h in (-1,1) is sent as SINGLE fp16.  W precision policy (round 11 = the
// round-8/10-proven policy on the proven round-7 structure):
//   k=0..223 (kc=0..6): SINGLE fp16 hi only (kc0-5 streamed, kc6 from LDS)
//   k=224..255 (kc=7, registers): split hi+lo (~2^-22 capture)
// B[k][n] = W_hh[n][k].  16x16x32 B-frag: lane holds B[n=lane&15][k=quad*8+j].
// Tile index = (k>>5)*48 + (j>>4); lane = (j&15) | (((k>>3)&3)<<4); short = k&7.
// Also WoT[k][p] = W_out[p][k]; also zeroes the phase-sync counter.
__global__ void pack_weights(const float* __restrict__ W_hh,
                             const float* __restrict__ W_out,
                             unsigned short* __restrict__ Bh,
                             unsigned short* __restrict__ Bl,
                             float* __restrict__ WoT,
                             unsigned int* __restrict__ ctr) {
    const int j = blockIdx.x;    // gate col 0..767
    const int k = threadIdx.x;   // h idx   0..255
    const float wv = W_hh[j * H_DIM + k];
    const unsigned short hi = f32_f16(wv);
    const float hf = (float)__builtin_bit_cast(_Float16, hi);
    const unsigned short lo = f32_f16(wv - hf);
    const int idx = (((k >> 5) * 48 + (j >> 4)) * 64 +
                     ((j & 15) | (((k >> 3) & 3) << 4))) * 8 + (k & 7);
    Bh[idx] = hi;
    Bl[idx] = lo;
    if (j < P_DIM) WoT[k * P_DIM + j] = W_out[j * H_DIM + k];
    if (j == 0 && k == 0) *ctr = 0u;   // d_ws is re-poisoned every launch
}

// LDS layout (84 KiB total; 1 block/CU by LDS anyway):
//   [0,       32768)  A-fragments (fp16), double-buffered:
//                     buf*16384 + chunk(kc*2+mt)*1024 + slot*16 + short*2
//                     (slot = rot3'd fragment-lane index)
//   [32768,   36864)  xtile[2][32][16] fp32
//   [36864,   86016)  W cache: 48 tiles x 1 KiB = kc=6 hi
//                     (index T=(gh>>1)*16+w*2+(gh&1))
#define A_OFF   0
#define X_OFF   32768
#define W_OFF   36864
#define LDS_SZ  86016

__device__ __forceinline__ void mfma2(floatx4& c0, floatx4& c1,
                                      const half8& a0, const half8& a1,
                                      const half8& bh, const half8& bl) {
    c0 = __builtin_amdgcn_mfma_f32_16x16x32_f16(a0, bh, c0, 0, 0, 0);
    c1 = __builtin_amdgcn_mfma_f32_16x16x32_f16(a1, bh, c1, 0, 0, 0);
    c0 = __builtin_amdgcn_mfma_f32_16x16x32_f16(a0, bl, c0, 0, 0, 0);
    c1 = __builtin_amdgcn_mfma_f32_16x16x32_f16(a1, bl, c1, 0, 0, 0);
}

// Issue 6 streamed hi-tile loads for one kc (stay in flight until MFMA use).
__device__ __forceinline__ void gissue1(half8 (&BH)[6],
                                        const unsigned short* (&pbh)[6],
                                        int kc) {
#pragma unroll
    for (int gh = 0; gh < 6; ++gh)
        BH[gh] = *(const half8*)(pbh[gh] + (size_t)kc * 24576);
}

__device__ __forceinline__ void ahread(half8 (&AH)[2], const char* Ac,
                                       int kc, int rl) {
#pragma unroll
    for (int mt = 0; mt < 2; ++mt)
        AH[mt] = *(const half8*)(Ac + (kc * 2 + mt) * 1024 + rl * 16);
}

// Single-precision kc block: 12 MFMAs (hi product only).
__device__ __forceinline__ void kcmfma1(floatx4 (&acc)[3][2][2],
                                        const half8 (&AH)[2],
                                        const half8 (&BH)[6]) {
#pragma unroll
    for (int gh = 0; gh < 6; ++gh) {
        floatx4& c0 = acc[gh >> 1][0][gh & 1];
        floatx4& c1 = acc[gh >> 1][1][gh & 1];
        c0 = __builtin_amdgcn_mfma_f32_16x16x32_f16(AH[0], BH[gh], c0, 0, 0, 0);
        c1 = __builtin_amdgcn_mfma_f32_16x16x32_f16(AH[1], BH[gh], c1, 0, 0, 0);
    }
}

// Split-precision kc block: 24 MFMAs (hi+lo) — used for kc7 (registers).
__device__ __forceinline__ void kcmfma(floatx4 (&acc)[3][2][2],
                                       const half8 (&AH)[2],
                                       const half8 (&BH)[6],
                                       const half8 (&BL)[6]) {
#pragma unroll
    for (int gh = 0; gh < 6; ++gh)
        mfma2(acc[gh >> 1][0][gh & 1], acc[gh >> 1][1][gh & 1],
              AH[0], AH[1], BH[gh], BL[gh]);
}

// Main persistent GRU kernel (round 11): the proven round-7 structure
// (1 block/CU, TB=32, 8 waves) with the round-8/10-proven precision policy
// (kc6 single-fp16) -> MFMA/wave/step 132->108, 6 fewer LDS reads.
// 2-blocks/CU is closed: failed via in-block waves (r2), VGPR spill (r8),
// and AGPR-gated co-residency + heartbeat timeout (r10).
// grid = 256 (1 block/CU), block = 512 (8 waves).
__global__ __launch_bounds__(512, 2)
void gru_mfma(const float* __restrict__ x,
              const float* __restrict__ W_ih,
              const float* __restrict__ b_ih,
              const float* __restrict__ b_hh,
              const unsigned short* __restrict__ Bh,
              const unsigned short* __restrict__ Bl,
              const float* __restrict__ WoT,   // [256][96]
              const float* __restrict__ b_out,
              float* __restrict__ out,
              unsigned int* __restrict__ ctr) {
    __shared__ __align__(16) char smem[LDS_SZ];

    const int tid  = threadIdx.x;
    const int w    = tid >> 6;     // wave 0..7
    const int lane = tid & 63;
    const int q    = lane >> 4;    // quad
    const int c    = lane & 15;
    const int row0 = blockIdx.x * TB;

    // Per-thread gate params; col = 256*g + 32*w + 16*ht + c
    float wih[3][2], bcc[2][2], bihn[2], bhhn[2];
#pragma unroll
    for (int g = 0; g < 3; ++g)
#pragma unroll
        for (int ht = 0; ht < 2; ++ht) {
            const int col = g * H_DIM + w * 32 + ht * 16 + c;
            wih[g][ht] = W_ih[col];
            if (g < 2) {
                bcc[g][ht] = b_ih[col] + b_hh[col];
            } else {
                bihn[ht] = b_ih[col];
                bhhn[ht] = b_hh[col];
            }
        }

    // Streamed-tile base pointers (per wave/lane), gh = g*2 + ht.
    const unsigned short* pbh[6];
    const unsigned short* pbl[6];
#pragma unroll
    for (int gh = 0; gh < 6; ++gh) {
        const size_t toff = (size_t)((gh >> 1) * 16 + w * 2 + (gh & 1)) * 512 + lane * 8;
        pbh[gh] = Bh + toff;
        pbl[gh] = Bl + toff;
    }

    // Register-resident weight tiles: kc=7 hi+lo.  (48 VGPRs)
    half8 r7h[6], r7l[6];
#pragma unroll
    for (int gh = 0; gh < 6; ++gh) {
        r7h[gh] = *(const half8*)(pbh[gh] + 7 * 24576);
        r7l[gh] = *(const half8*)(pbl[gh] + 7 * 24576);
    }

    // LDS weight cache staging: 48 tiles = kc=6 hi only.
    for (int i = tid; i < 48 * 64; i += 512) {
        const int slot = i >> 6, l16 = i & 63;
        const unsigned short* src = Bh + (size_t)(288 + slot) * 512 + l16 * 8;
        *(uint4*)(smem + W_OFF + slot * 1024 + l16 * 16) = *(const uint4*)src;
    }

    // Zero both A-frag buffers (h0 = 0) and stage x for t=0..15.
    for (int i = tid; i < 8192; i += 512) ((int*)(smem + A_OFF))[i] = 0;
    float* xt = (float*)(smem + X_OFF);
    {
        const int r = tid >> 4, t2 = tid & 15;
        xt[r * 16 + t2] = x[(size_t)(row0 + r) * S_LEN + t2];
    }
    __syncthreads();

    // h_old in C-frag layout: element (mt,ht,reg) = h[4q+reg+16mt][32w+16ht+c]
    float h_own[2][2][4];
#pragma unroll
    for (int mt = 0; mt < 2; ++mt)
#pragma unroll
        for (int ht = 0; ht < 2; ++ht)
#pragma unroll
            for (int r = 0; r < 4; ++r) h_own[mt][ht][r] = 0.0f;

    const int rl = rot3(lane);

    // Loop-invariant precompute: scatter byte offsets (within a chunk) for
    // each (ht,r), x-tile row offsets for each (mt,r), kc6 LDS tile bases.
    int soff[2][4];                 // [ht][r] -> rot3(d)*16 + (c&7)*2
#pragma unroll
    for (int ht = 0; ht < 2; ++ht)
#pragma unroll
        for (int r = 0; r < 4; ++r) {
            const int d = (q * 4 + r) | ((2 * ht + (c >> 3)) << 4);
            soff[ht][r] = rot3(d) * 16 + (c & 7) * 2;
        }
    int xbase[2][4];                // [mt][r] -> (q*4+r+16mt)*16
#pragma unroll
    for (int mt = 0; mt < 2; ++mt)
#pragma unroll
        for (int r = 0; r < 4; ++r)
            xbase[mt][r] = (q * 4 + r + 16 * mt) * 16;
    const char* w6base[6];          // kc6 hi tile
#pragma unroll
    for (int gh = 0; gh < 6; ++gh) {
        const int T = (gh >> 1) * 16 + w * 2 + (gh & 1);
        w6base[gh] = smem + W_OFF + T * 1024 + lane * 16;
    }

    // Pipeline buffers (static names only — rule: no runtime indexing).
    half8 b0h[6], b1h[6];
    half8 ahA[2], ahB[2];

    // Prologue: kc=0 of step 0 in flight before the loop.
    gissue1(b0h, pbh, 0);

#pragma unroll 1
    for (int t = 0; t < S_LEN; ++t) {
        // Defeat LICM of the (t-invariant) streamed loads: make the stream
        // pointers opaque each iteration so loads stay inside the loop.
#pragma unroll
        for (int gh = 0; gh < 6; ++gh)
            asm volatile("" : "+v"(pbh[gh]));

        const int cur = t & 1, nxt = cur ^ 1;
        const char* Ac = smem + A_OFF + cur * 16384;

        ahread(ahA, Ac, 0, rl);            // A-frags for kc=0
        gissue1(b1h, pbh, 1);              // kc=1 stream in flight

        // x for my 8 rows (LDS broadcast); xidx is wave-uniform per step.
        const int xidx = ((t >> 4) & 1) * 512 + (t & 15);
        float xr[2][4];
#pragma unroll
        for (int mt = 0; mt < 2; ++mt)
#pragma unroll
            for (int r = 0; r < 4; ++r)
                xr[mt][r] = xt[xbase[mt][r] + xidx];

        // C frags [gate][mt][ht]; fold x-side pre-activation + bias into init.
        floatx4 acc[3][2][2];
#pragma unroll
        for (int mt = 0; mt < 2; ++mt)
#pragma unroll
            for (int ht = 0; ht < 2; ++ht)
#pragma unroll
                for (int r = 0; r < 4; ++r) {
                    acc[0][mt][ht][r] = fmaf(xr[mt][r], wih[0][ht], bcc[0][ht]);
                    acc[1][mt][ht][r] = fmaf(xr[mt][r], wih[1][ht], bcc[1][ht]);
                    acc[2][mt][ht][r] = bhhn[ht];
                }

        // ---- Pipelined kc ladder (single-fp16 stream): consume kc,
        //      stream kc+1, read A(kc+1) ----
        ahread(ahB, Ac, 1, rl);
        kcmfma1(acc, ahA, b0h);                           // kc0
        gissue1(b0h, pbh, 2);
        ahread(ahA, Ac, 2, rl);
        kcmfma1(acc, ahB, b1h);                           // kc1
        gissue1(b1h, pbh, 3);
        ahread(ahB, Ac, 3, rl);
        kcmfma1(acc, ahA, b0h);                           // kc2
        gissue1(b0h, pbh, 4);
        ahread(ahA, Ac, 4, rl);
        kcmfma1(acc, ahB, b1h);                           // kc3
        gissue1(b1h, pbh, 5);
        ahread(ahB, Ac, 5, rl);
        kcmfma1(acc, ahA, b0h);                           // kc4
        ahread(ahA, Ac, 6, rl);
        kcmfma1(acc, ahB, b1h);                           // kc5

        // ---- kc6: hi from the LDS cache (single precision) ----
        {
            half8 w6h[6];
#pragma unroll
            for (int gh = 0; gh < 6; ++gh)
                w6h[gh] = *(const half8*)(w6base[gh]);
            ahread(ahB, Ac, 7, rl);
            kcmfma1(acc, ahA, w6h);                       // kc6
        }

        // Prefetch next step's kc0 while kc7 + gates + barrier run
        // (weights are t-invariant: same addresses every step, no guard).
        gissue1(b0h, pbh, 0);
        kcmfma(acc, ahB, r7h, r7l);                       // kc7 (split)

        // Gates + h update (in-register); scatter next A-frags (rot3-swizzled).
        char* Anx = smem + A_OFF + nxt * 16384;
#pragma unroll
        for (int mt = 0; mt < 2; ++mt) {
            char* ch = Anx + (w * 2 + mt) * 1024;         // chunk kc=w
#pragma unroll
            for (int ht = 0; ht < 2; ++ht)
#pragma unroll
                for (int r = 0; r < 4; ++r) {
                    const float rr  = sigmoid_fast(acc[0][mt][ht][r]);
                    const float zz  = sigmoid_fast(acc[1][mt][ht][r]);
                    const float inn = fmaf(xr[mt][r], wih[2][ht], bihn[ht]);
                    const float nn  = tanh_fast(fmaf(rr, acc[2][mt][ht][r], inn));
                    const float hv  = (1.0f - zz) * nn + zz * h_own[mt][ht][r];
                    h_own[mt][ht][r] = hv;
                    *(unsigned short*)(ch + soff[ht][r]) = f32_f16(hv);
                }
        }

        // Re-stage x for the next 16 steps (into the idle x buffer).
        const bool tick = ((t & 15) == 15) && (t != S_LEN - 1);
        if (tick) {
            const int r = tid >> 4, t2 = tid & 15;
            xt[((((t + 1) >> 4) & 1) * 32 + r) * 16 + t2] =
                x[(size_t)(row0 + r) * S_LEN + (t + 1) + t2];
        }
        __syncthreads();   // single barrier: next A-frags + x tile visible

        // Phase-alignment heartbeat every 16 steps: keeps all 256 blocks'
        // weight streams in phase so the per-XCD L2 working set stays hot.
        // Safe here: grid == 256 == CU count, all blocks co-resident.
        if (tick) {
            if (tid == 0) {
                const unsigned int tgt = 256u * (unsigned)((t >> 4) + 1);
                atomicAdd(ctr, 1u);
                for (int spin = 0; spin < (1 << 17); ++spin) {
                    if (__hip_atomic_load(ctr, __ATOMIC_RELAXED,
                                          __HIP_MEMORY_SCOPE_AGENT) >= tgt) break;
                    __builtin_amdgcn_s_sleep(4);
                }
            }
            __syncthreads();
        }
    }

    // -------- Epilogue: dump final h (fp32, from registers) and project.
    float* hfin = (float*)(smem);   // reuse A region: [32][256] = 32 KiB
#pragma unroll
    for (int mt = 0; mt < 2; ++mt)
#pragma unroll
        for (int ht = 0; ht < 2; ++ht)
#pragma unroll
            for (int r = 0; r < 4; ++r) {
                const int m = q * 4 + r + 16 * mt;
                const int k = w * 32 + ht * 16 + c;
                hfin[m * H_DIM + k] = h_own[mt][ht][r];
            }
    __syncthreads();

    if (tid < 256) {
        const int cid   = tid & 63;
        const int rid   = tid >> 6;
        const int myrow = rid * 8;
        const int pA    = cid;
        const int pB    = 64 + cid;
        const bool hasB = (cid < 32);
        float accA[8], accB[8];
#pragma unroll
        for (int rr = 0; rr < 8; ++rr) { accA[rr] = 0.0f; accB[rr] = 0.0f; }

        for (int k = 0; k < H_DIM; k += 4) {
            float4 hv[8];
#pragma unroll
            for (int rr = 0; rr < 8; ++rr)
                hv[rr] = *(const float4*)&hfin[(myrow + rr) * H_DIM + k];
            float wA[4], wB[4];
#pragma unroll
            for (int kk = 0; kk < 4; ++kk) {
                wA[kk] = WoT[(size_t)(k + kk) * P_DIM + pA];
                wB[kk] = hasB ? WoT[(size_t)(k + kk) * P_DIM + pB] : 0.0f;
            }
#pragma unroll
            for (int kk = 0; kk < 4; ++kk)
#pragma unroll
                for (int rr = 0; rr < 8; ++rr) {
                    const float hvv = (&hv[rr].x)[kk];
                    accA[rr] = fmaf(hvv, wA[kk], accA[rr]);
                    accB[rr] = fmaf(hvv, wB[kk], accB[rr]);
                }
        }
        const float boA = b_out[pA];
        const float boB = hasB ? b_out[pB] : 0.0f;
#pragma unroll
        for (int rr = 0; rr < 8; ++rr) {
            const size_t orow = (size_t)(row0 + myrow + rr) * P_DIM;
            out[orow + pA] = accA[rr] + boA;
            if (hasB) out[orow + pB] = accB[rr] + boB;
        }
    }
}

// -------- fp32 fallback — used only if ws_size is too small.
__global__ __launch_bounds__(256, 1)
void gru_fallback(const float* __restrict__ x,
                  const float* __restrict__ W_ih,
                  const float* __restrict__ Whh,
                  const float* __restrict__ b_ih,
                  const float* __restrict__ b_hh,
                  const float* __restrict__ Wout,
                  const float* __restrict__ b_out,
                  float* __restrict__ out) {
    __shared__ float hbuf[2][TB][H_DIM];

    const int tid   = threadIdx.x;
    const int cid   = tid & 63;
    const int rid   = tid >> 6;
    const int row0  = blockIdx.x * TB;
    const int myrow = rid * 8;
    const int c0    = cid * 4;

    float wih[3][4], bc[2][4], bihn[4], bhhn[4];
#pragma unroll
    for (int cc = 0; cc < 4; ++cc) {
        const int j = c0 + cc;
        wih[0][cc] = W_ih[j];
        wih[1][cc] = W_ih[H_DIM + j];
        wih[2][cc] = W_ih[2 * H_DIM + j];
        bc[0][cc]  = b_ih[j] + b_hh[j];
        bc[1][cc]  = b_ih[H_DIM + j] + b_hh[H_DIM + j];
        bihn[cc]   = b_ih[2 * H_DIM + j];
        bhhn[cc]   = b_hh[2 * H_DIM + j];
    }
    for (int i = tid; i < TB * H_DIM; i += 256) (&hbuf[0][0][0])[i] = 0.0f;
    float h_own[8][4];
#pragma unroll
    for (int rr = 0; rr < 8; ++rr)
#pragma unroll
        for (int cc = 0; cc < 4; ++cc) h_own[rr][cc] = 0.0f;
    __syncthreads();

    int p = 0;
    for (int t = 0; t < S_LEN; ++t) {
        float xv[8];
#pragma unroll
        for (int rr = 0; rr < 8; ++rr)
            xv[rr] = x[(size_t)(row0 + myrow + rr) * S_LEN + t];

        float acc[3][8][4];
#pragma unroll
        for (int rr = 0; rr < 8; ++rr)
#pragma unroll
            for (int cc = 0; cc < 4; ++cc) {
                acc[0][rr][cc] = fmaf(xv[rr], wih[0][cc], bc[0][cc]);
                acc[1][rr][cc] = fmaf(xv[rr], wih[1][cc], bc[1][cc]);
                acc[2][rr][cc] = bhhn[cc];
            }
        const float* hb = &hbuf[p][0][0];
        for (int k = 0; k < H_DIM; k += 4) {
            float4 hv[8];
#pragma unroll
            for (int rr = 0; rr < 8; ++rr)
                hv[rr] = *(const float4*)(hb + (myrow + rr) * H_DIM + k);
#pragma unroll
            for (int g = 0; g < 3; ++g)
#pragma unroll
                for (int kk = 0; kk < 4; ++kk) {
                    float wrow[4];
#pragma unroll
                    for (int cc = 0; cc < 4; ++cc)
                        wrow[cc] = Whh[(size_t)(g * H_DIM + c0 + cc) * H_DIM + k + kk];
#pragma unroll
                    for (int rr = 0; rr < 8; ++rr) {
                        const float hvv = (&hv[rr].x)[kk];
#pragma unroll
                        for (int cc = 0; cc < 4; ++cc)
                            acc[g][rr][cc] = fmaf(hvv, wrow[cc], acc[g][rr][cc]);
                    }
                }
        }
#pragma unroll
        for (int rr = 0; rr < 8; ++rr) {
            float4 hnew;
#pragma unroll
            for (int cc = 0; cc < 4; ++cc) {
                const float r_  = sigmoid_fast(acc[0][rr][cc]);
                const float z_  = sigmoid_fast(acc[1][rr][cc]);
                const float i_n = fmaf(xv[rr], wih[2][cc], bihn[cc]);
                const float n_  = tanh_fast(fmaf(r_, acc[2][rr][cc], i_n));
                const float hv2 = (1.0f - z_) * n_ + z_ * h_own[rr][cc];
                h_own[rr][cc] = hv2;
                (&hnew.x)[cc] = hv2;
            }
            *(float4*)&hbuf[1 - p][myrow + rr][c0] = hnew;
        }
        __syncthreads();
        p ^= 1;
    }

    const int  pA   = cid;
    const int  pB   = 64 + cid;
    const bool hasB = (cid < 32);
    float accA[8], accB[8];
#pragma unroll
    for (int rr = 0; rr < 8; ++rr) { accA[rr] = 0.0f; accB[rr] = 0.0f; }
    for (int k = 0; k < H_DIM; k += 4) {
        float4 hv[8];
#pragma unroll
        for (int rr = 0; rr < 8; ++rr)
            hv[rr] = *(const float4*)&hbuf[p][myrow + rr][k];
        float wA[4], wB[4];
#pragma unroll
        for (int kk = 0; kk < 4; ++kk) {
            wA[kk] = Wout[(size_t)pA * H_DIM + k + kk];
            wB[kk] = hasB ? Wout[(size_t)pB * H_DIM + k + kk] : 0.0f;
        }
#pragma unroll
        for (int kk = 0; kk < 4; ++kk)
#pragma unroll
            for (int rr = 0; rr < 8; ++rr) {
                const float hvv = (&hv[rr].x)[kk];
                accA[rr] = fmaf(hvv, wA[kk], accA[rr]);
                accB[rr] = fmaf(hvv, wB[kk], accB[rr]);
            }
    }
    const float boA = b_out[pA];
    const float boB = hasB ? b_out[pB] : 0.0f;
#pragma unroll
    for (int rr = 0; rr < 8; ++rr) {
        const size_t orow = (size_t)(row0 + myrow + rr) * P_DIM;
        out[orow + pA] = accA[rr] + boA;
        if (hasB) out[orow + pB] = accB[rr] + boB;
    }
}

extern "C" void kernel_launch(void* const* d_in, const int* in_sizes, int n_in,
                              void* d_out, int out_size, void* d_ws, size_t ws_size,
                              hipStream_t stream) {
    const float* x     = (const float*)d_in[0];
    const float* W_ih  = (const float*)d_in[1];
    const float* W_hh  = (const float*)d_in[2];
    const float* b_ih  = (const float*)d_in[3];
    const float* b_hh  = (const float*)d_in[4];
    const float* W_out = (const float*)d_in[5];
    const float* b_out = (const float*)d_in[6];
    float* out = (float*)d_out;

    const size_t bpack_elems = 8 * 48 * 64 * 8;          // 196608 f16 per matrix
    const size_t wot_elems   = (size_t)H_DIM * P_DIM;    // 24576 fp32
    const size_t ctr_off = bpack_elems * 2 * sizeof(unsigned short) * 2 +
                           wot_elems * sizeof(float);    // 1671168 B (16-aligned)
    const size_t need = ctr_off + sizeof(unsigned int);

    if (ws_size >= need) {
        unsigned short* Bh = (unsigned short*)d_ws;
        unsigned short* Bl = Bh + bpack_elems * 2;
        float* WoT = (float*)(Bl + bpack_elems * 2);
        unsigned int* ctr = (unsigned int*)((char*)d_ws + ctr_off);
        pack_weights<<<G3, H_DIM, 0, stream>>>(W_hh, W_out, Bh, Bl, WoT, ctr);
        gru_mfma<<<B_ROWS / TB, 512, 0, stream>>>(x, W_ih, b_ih, b_hh,
                                                  Bh, Bl, WoT, b_out, out, ctr);
    } else {
        gru_fallback<<<B_ROWS / TB, 256, 0, stream>>>(x, W_ih, W_hh, b_ih, b_hh,
                                                      W_out, b_out, out);
    }
}

// Round 12
// 3304.420 us; speedup vs baseline: 248.7871x; 1.0539x over previous
//
#include <hip/hip_runtime.h>
#include <math.h>

// Problem constants
#define B_ROWS 8192
#define S_LEN  512
#define H_DIM  256
#define G3     768          // 3*H
#define P_DIM  96
#define TB     32           // batch rows per block

typedef __attribute__((ext_vector_type(8))) _Float16 half8;  // 8 f16 (4 VGPRs)
typedef __attribute__((ext_vector_type(4))) float floatx4;   // MFMA C/D frag

__device__ __forceinline__ float sigmoid_fast(float v) {
    return 1.0f / (1.0f + __expf(-v));
}
__device__ __forceinline__ float tanh_fast(float v) {
    return 1.0f - 2.0f / (__expf(2.0f * v) + 1.0f);
}
__device__ __forceinline__ unsigned short f32_f16(float f) {
    _Float16 h = (_Float16)f;                 // RTN
    return __builtin_bit_cast(unsigned short, h);
}
// Involutive 6-bit lane rotation: spreads scatter dest-lanes across bank groups.
__device__ __forceinline__ int rot3(int l) { return ((l << 3) | (l >> 3)) & 63; }

// -------- One-time weight pack: W_hh -> per-lane MFMA B-fragments (hi/lo fp16).
// h in (-1,1) is sent as SINGLE fp16.  W precision policy (round-11-proven):
//   k=0..223 (kc=0..6): SINGLE fp16 hi only (kc0-5 streamed, kc6 from LDS)
//   k=224..255 (kc=7, registers): split hi+lo (~2^-22 capture)
// B[k][n] = W_hh[n][k].  16x16x32 B-frag: lane holds B[n=lane&15][k=quad*8+j].
// Tile index = (k>>5)*48 + (j>>4); lane = (j&15) | (((k>>3)&3)<<4); short = k&7.
// Also WoT[k][p] = W_out[p][k]; also zeroes the phase-sync counter.
__global__ void pack_weights(const float* __restrict__ W_hh,
                             const float* __restrict__ W_out,
                             unsigned short* __restrict__ Bh,
                             unsigned short* __restrict__ Bl,
                             float* __restrict__ WoT,
                             unsigned int* __restrict__ ctr) {
    const int j = blockIdx.x;    // gate col 0..767
    const int k = threadIdx.x;   // h idx   0..255
    const float wv = W_hh[j * H_DIM + k];
    const unsigned short hi = f32_f16(wv);
    const float hf = (float)__builtin_bit_cast(_Float16, hi);
    const unsigned short lo = f32_f16(wv - hf);
    const int idx = (((k >> 5) * 48 + (j >> 4)) * 64 +
                     ((j & 15) | (((k >> 3) & 3) << 4))) * 8 + (k & 7);
    Bh[idx] = hi;
    Bl[idx] = lo;
    if (j < P_DIM) WoT[k * P_DIM + j] = W_out[j * H_DIM + k];
    if (j == 0 && k == 0) *ctr = 0u;   // d_ws is re-poisoned every launch
}

// LDS layout (84 KiB total; 1 block/CU):
//   [0,       32768)  A-fragments (fp16), double-buffered:
//                     buf*16384 + chunk(kc*2+mt)*1024 + slot*16 + short*2
//                     (slot = rot3'd fragment-lane index)
//   [32768,   36864)  xtile[2][32][16] fp32
//   [36864,   86016)  W cache: 48 tiles x 1 KiB = kc=6 hi (index T=g*16+wv)
#define A_OFF   0
#define X_OFF   32768
#define W_OFF   36864
#define LDS_SZ  86016

// Issue 3 streamed hi-tile loads for one kc (stay in flight until MFMA use).
__device__ __forceinline__ void gissue1(half8 (&BH)[3],
                                        const unsigned short* (&pbh)[3],
                                        int kc) {
#pragma unroll
    for (int g = 0; g < 3; ++g)
        BH[g] = *(const half8*)(pbh[g] + (size_t)kc * 24576);
}

__device__ __forceinline__ void ahread(half8 (&AH)[2], const char* Ac,
                                       int kc, int rl) {
#pragma unroll
    for (int mt = 0; mt < 2; ++mt)
        AH[mt] = *(const half8*)(Ac + (kc * 2 + mt) * 1024 + rl * 16);
}

// Single-precision kc block: 6 MFMAs (hi product only).
__device__ __forceinline__ void kcmfma1(floatx4 (&acc)[3][2],
                                        const half8 (&AH)[2],
                                        const half8 (&BH)[3]) {
#pragma unroll
    for (int g = 0; g < 3; ++g) {
        acc[g][0] = __builtin_amdgcn_mfma_f32_16x16x32_f16(AH[0], BH[g], acc[g][0], 0, 0, 0);
        acc[g][1] = __builtin_amdgcn_mfma_f32_16x16x32_f16(AH[1], BH[g], acc[g][1], 0, 0, 0);
    }
}

// Split-precision kc block: 12 MFMAs (hi+lo) — used for kc7 (registers).
__device__ __forceinline__ void kcmfma2(floatx4 (&acc)[3][2],
                                        const half8 (&AH)[2],
                                        const half8 (&BH)[3],
                                        const half8 (&BL)[3]) {
#pragma unroll
    for (int g = 0; g < 3; ++g) {
        acc[g][0] = __builtin_amdgcn_mfma_f32_16x16x32_f16(AH[0], BH[g], acc[g][0], 0, 0, 0);
        acc[g][1] = __builtin_amdgcn_mfma_f32_16x16x32_f16(AH[1], BH[g], acc[g][1], 0, 0, 0);
        acc[g][0] = __builtin_amdgcn_mfma_f32_16x16x32_f16(AH[0], BL[g], acc[g][0], 0, 0, 0);
        acc[g][1] = __builtin_amdgcn_mfma_f32_16x16x32_f16(AH[1], BL[g], acc[g][1], 0, 0, 0);
    }
}

// Main persistent GRU kernel (round 12): ONE 1024-thread block per CU ->
// 16 waves = 4 waves/SIMD from a single block.  __launch_bounds__(1024,1)
// caps VGPR at 128 (16 waves x 128 = full file) — rounds 2/8/10 all failed
// this shape ONLY because their launch_bounds demanded multi-block minima
// (VGPR 64 -> scratch spill, or AGPR-gated residency).  Per-wave state is
// halved (each wave owns 16 gate-cols), so 128 VGPRs fit without spill.
// 4 waves/SIMD double the latency-hiding inside both the MFMA ladder and
// the VALU/trans gate phase (measured: ~50% of each step was pipe-idle
// stall at 2 waves/SIMD).  Per-CU work totals unchanged vs round 11.
// grid = 256 (1 block/CU), block = 1024 (16 waves).
__global__ __launch_bounds__(1024, 1)
void gru_mfma(const float* __restrict__ x,
              const float* __restrict__ W_ih,
              const float* __restrict__ b_ih,
              const float* __restrict__ b_hh,
              const unsigned short* __restrict__ Bh,
              const unsigned short* __restrict__ Bl,
              const float* __restrict__ WoT,   // [256][96]
              const float* __restrict__ b_out,
              float* __restrict__ out,
              unsigned int* __restrict__ ctr) {
    __shared__ __align__(16) char smem[LDS_SZ];

    const int tid  = threadIdx.x;
    const int wv   = tid >> 6;     // wave 0..15; owns gate-cols g*256 + wv*16 + c
    const int lane = tid & 63;
    const int q    = lane >> 4;    // quad
    const int c    = lane & 15;
    const int row0 = blockIdx.x * TB;

    // Per-thread gate params; col = 256*g + 16*wv + c
    float wih[3], bcc[2], bihn, bhhn;
#pragma unroll
    for (int g = 0; g < 3; ++g) {
        const int col = g * H_DIM + wv * 16 + c;
        wih[g] = W_ih[col];
        if (g < 2) {
            bcc[g] = b_ih[col] + b_hh[col];
        } else {
            bihn = b_ih[col];
            bhhn = b_hh[col];
        }
    }

    // Streamed-tile base pointers (per wave/lane); tile index T = g*16 + wv.
    const unsigned short* pbh[3];
#pragma unroll
    for (int g = 0; g < 3; ++g)
        pbh[g] = Bh + (size_t)(g * 16 + wv) * 512 + lane * 8;

    // Register-resident weight tiles: kc=7 hi+lo.  (24 VGPRs)
    half8 r7h[3], r7l[3];
#pragma unroll
    for (int g = 0; g < 3; ++g) {
        const size_t toff = (size_t)(g * 16 + wv) * 512 + lane * 8;
        r7h[g] = *(const half8*)(Bh + toff + 7 * 24576);
        r7l[g] = *(const half8*)(Bl + toff + 7 * 24576);
    }

    // LDS weight cache staging: 48 tiles = kc=6 hi only.
    for (int i = tid; i < 48 * 64; i += 1024) {
        const int slot = i >> 6, l16 = i & 63;
        const unsigned short* src = Bh + (size_t)(288 + slot) * 512 + l16 * 8;
        *(uint4*)(smem + W_OFF + slot * 1024 + l16 * 16) = *(const uint4*)src;
    }

    // Zero both A-frag buffers (h0 = 0) and stage x for t=0..15.
    for (int i = tid; i < 8192; i += 1024) ((int*)(smem + A_OFF))[i] = 0;
    float* xt = (float*)(smem + X_OFF);
    if (tid < 512) {
        const int r = tid >> 4, t2 = tid & 15;
        xt[r * 16 + t2] = x[(size_t)(row0 + r) * S_LEN + t2];
    }
    __syncthreads();

    // h_old in C-frag layout: element (mt,reg) = h[4q+reg+16mt][16wv+c]
    float h_own[2][4];
#pragma unroll
    for (int mt = 0; mt < 2; ++mt)
#pragma unroll
        for (int r = 0; r < 4; ++r) h_own[mt][r] = 0.0f;

    const int rl = rot3(lane);

    // Loop-invariant precompute.
    const int hchunk = (wv >> 1) * 2;           // A-chunk pair this wave scatters
    const int cg     = 2 * (wv & 1) + (c >> 3); // col-group within chunk
    int soff[4];                                // [r] -> rot3(d)*16 + (c&7)*2
#pragma unroll
    for (int r = 0; r < 4; ++r) {
        const int d = (q * 4 + r) | (cg << 4);
        soff[r] = rot3(d) * 16 + (c & 7) * 2;
    }
    int xbase[2][4];                            // [mt][r] -> (q*4+r+16mt)*16
#pragma unroll
    for (int mt = 0; mt < 2; ++mt)
#pragma unroll
        for (int r = 0; r < 4; ++r)
            xbase[mt][r] = (q * 4 + r + 16 * mt) * 16;
    const char* w6base[3];                      // kc6 hi tile, T = g*16+wv
#pragma unroll
    for (int g = 0; g < 3; ++g)
        w6base[g] = smem + W_OFF + (g * 16 + wv) * 1024 + lane * 16;

    // Pipeline buffers (static names only — rule: no runtime indexing).
    half8 b0h[3], b1h[3];
    half8 ahA[2], ahB[2];

    // Prologue: kc=0 of step 0 in flight before the loop.
    gissue1(b0h, pbh, 0);

#pragma unroll 1
    for (int t = 0; t < S_LEN; ++t) {
        // Defeat LICM of the (t-invariant) streamed loads.
#pragma unroll
        for (int g = 0; g < 3; ++g)
            asm volatile("" : "+v"(pbh[g]));

        const int cur = t & 1, nxt = cur ^ 1;
        const char* Ac = smem + A_OFF + cur * 16384;

        ahread(ahA, Ac, 0, rl);            // A-frags for kc=0
        gissue1(b1h, pbh, 1);              // kc=1 stream in flight

        // x for my 8 rows (LDS broadcast); xidx is wave-uniform per step.
        const int xidx = ((t >> 4) & 1) * 512 + (t & 15);
        float xr[2][4];
#pragma unroll
        for (int mt = 0; mt < 2; ++mt)
#pragma unroll
            for (int r = 0; r < 4; ++r)
                xr[mt][r] = xt[xbase[mt][r] + xidx];

        // C frags [gate][mt]; fold x-side pre-activation + bias into init.
        floatx4 acc[3][2];
#pragma unroll
        for (int mt = 0; mt < 2; ++mt)
#pragma unroll
            for (int r = 0; r < 4; ++r) {
                acc[0][mt][r] = fmaf(xr[mt][r], wih[0], bcc[0]);
                acc[1][mt][r] = fmaf(xr[mt][r], wih[1], bcc[1]);
                acc[2][mt][r] = bhhn;
            }

        // ---- Pipelined kc ladder (single-fp16 stream): consume kc,
        //      stream kc+1, read A(kc+1) ----
        ahread(ahB, Ac, 1, rl);
        kcmfma1(acc, ahA, b0h);                           // kc0
        gissue1(b0h, pbh, 2);
        ahread(ahA, Ac, 2, rl);
        kcmfma1(acc, ahB, b1h);                           // kc1
        gissue1(b1h, pbh, 3);
        ahread(ahB, Ac, 3, rl);
        kcmfma1(acc, ahA, b0h);                           // kc2
        gissue1(b0h, pbh, 4);
        ahread(ahA, Ac, 4, rl);
        kcmfma1(acc, ahB, b1h);                           // kc3
        gissue1(b1h, pbh, 5);
        ahread(ahB, Ac, 5, rl);
        kcmfma1(acc, ahA, b0h);                           // kc4
        ahread(ahA, Ac, 6, rl);
        kcmfma1(acc, ahB, b1h);                           // kc5

        // ---- kc6: hi from the LDS cache (single precision) ----
        {
            half8 w6h[3];
#pragma unroll
            for (int g = 0; g < 3; ++g)
                w6h[g] = *(const half8*)(w6base[g]);
            ahread(ahB, Ac, 7, rl);
            kcmfma1(acc, ahA, w6h);                       // kc6
        }

        // Prefetch next step's kc0 while kc7 + gates + barrier run.
        gissue1(b0h, pbh, 0);
        kcmfma2(acc, ahB, r7h, r7l);                      // kc7 (split)

        // Gates + h update (in-register); scatter next A-frags (rot3-swizzled).
        char* Anx = smem + A_OFF + nxt * 16384;
#pragma unroll
        for (int mt = 0; mt < 2; ++mt) {
            char* ch = Anx + (hchunk + mt) * 1024;        // chunk kc = wv>>1
#pragma unroll
            for (int r = 0; r < 4; ++r) {
                const float rr  = sigmoid_fast(acc[0][mt][r]);
                const float zz  = sigmoid_fast(acc[1][mt][r]);
                const float inn = fmaf(xr[mt][r], wih[2], bihn);
                const float nn  = tanh_fast(fmaf(rr, acc[2][mt][r], inn));
                const float hv  = (1.0f - zz) * nn + zz * h_own[mt][r];
                h_own[mt][r] = hv;
                *(unsigned short*)(ch + soff[r]) = f32_f16(hv);
            }
        }

        // Re-stage x for the next 16 steps (into the idle x buffer).
        const bool tick = ((t & 15) == 15) && (t != S_LEN - 1);
        if (tick && tid < 512) {
            const int r = tid >> 4, t2 = tid & 15;
            xt[((((t + 1) >> 4) & 1) * 32 + r) * 16 + t2] =
                x[(size_t)(row0 + r) * S_LEN + (t + 1) + t2];
        }
        __syncthreads();   // single barrier: next A-frags + x tile visible

        // Phase-alignment heartbeat every 16 steps: keeps all 256 blocks'
        // weight streams in phase so the per-XCD L2 working set stays hot.
        // Safe: grid == 256 == CU count, all blocks co-resident.
        if (tick) {
            if (tid == 0) {
                const unsigned int tgt = 256u * (unsigned)((t >> 4) + 1);
                atomicAdd(ctr, 1u);
                for (int spin = 0; spin < (1 << 17); ++spin) {
                    if (__hip_atomic_load(ctr, __ATOMIC_RELAXED,
                                          __HIP_MEMORY_SCOPE_AGENT) >= tgt) break;
                    __builtin_amdgcn_s_sleep(4);
                }
            }
            __syncthreads();
        }
    }

    // -------- Epilogue: dump final h (fp32, from registers) and project.
    float* hfin = (float*)(smem);   // reuse A region: [32][256] = 32 KiB
#pragma unroll
    for (int mt = 0; mt < 2; ++mt)
#pragma unroll
        for (int r = 0; r < 4; ++r) {
            const int m = q * 4 + r + 16 * mt;
            const int k = wv * 16 + c;
            hfin[m * H_DIM + k] = h_own[mt][r];
        }
    __syncthreads();

    if (tid < 256) {
        const int cid   = tid & 63;
        const int rid   = tid >> 6;
        const int myrow = rid * 8;
        const int pA    = cid;
        const int pB    = 64 + cid;
        const bool hasB = (cid < 32);
        float accA[8], accB[8];
#pragma unroll
        for (int rr = 0; rr < 8; ++rr) { accA[rr] = 0.0f; accB[rr] = 0.0f; }

        for (int k = 0; k < H_DIM; k += 4) {
            float4 hv[8];
#pragma unroll
            for (int rr = 0; rr < 8; ++rr)
                hv[rr] = *(const float4*)&hfin[(myrow + rr) * H_DIM + k];
            float wA[4], wB[4];
#pragma unroll
            for (int kk = 0; kk < 4; ++kk) {
                wA[kk] = WoT[(size_t)(k + kk) * P_DIM + pA];
                wB[kk] = hasB ? WoT[(size_t)(k + kk) * P_DIM + pB] : 0.0f;
            }
#pragma unroll
            for (int kk = 0; kk < 4; ++kk)
#pragma unroll
                for (int rr = 0; rr < 8; ++rr) {
                    const float hvv = (&hv[rr].x)[kk];
                    accA[rr] = fmaf(hvv, wA[kk], accA[rr]);
                    accB[rr] = fmaf(hvv, wB[kk], accB[rr]);
                }
        }
        const float boA = b_out[pA];
        const float boB = hasB ? b_out[pB] : 0.0f;
#pragma unroll
        for (int rr = 0; rr < 8; ++rr) {
            const size_t orow = (size_t)(row0 + myrow + rr) * P_DIM;
            out[orow + pA] = accA[rr] + boA;
            if (hasB) out[orow + pB] = accB[rr] + boB;
        }
    }
}

// -------- fp32 fallback — used only if ws_size is too small.
__global__ __launch_bounds__(256, 1)
void gru_fallback(const float* __restrict__ x,
                  const float* __restrict__ W_ih,
                  const float* __restrict__ Whh,
                  const float* __restrict__ b_ih,
                  const float* __restrict__ b_hh,
                  const float* __restrict__ Wout,
                  const float* __restrict__ b_out,
                  float* __restrict__ out) {
    __shared__ float hbuf[2][TB][H_DIM];

    const int tid   = threadIdx.x;
    const int cid   = tid & 63;
    const int rid   = tid >> 6;
    const int row0  = blockIdx.x * TB;
    const int myrow = rid * 8;
    const int c0    = cid * 4;

    float wih[3][4], bc[2][4], bihn[4], bhhn[4];
#pragma unroll
    for (int cc = 0; cc < 4; ++cc) {
        const int j = c0 + cc;
        wih[0][cc] = W_ih[j];
        wih[1][cc] = W_ih[H_DIM + j];
        wih[2][cc] = W_ih[2 * H_DIM + j];
        bc[0][cc]  = b_ih[j] + b_hh[j];
        bc[1][cc]  = b_ih[H_DIM + j] + b_hh[H_DIM + j];
        bihn[cc]   = b_ih[2 * H_DIM + j];
        bhhn[cc]   = b_hh[2 * H_DIM + j];
    }
    for (int i = tid; i < TB * H_DIM; i += 256) (&hbuf[0][0][0])[i] = 0.0f;
    float h_own[8][4];
#pragma unroll
    for (int rr = 0; rr < 8; ++rr)
#pragma unroll
        for (int cc = 0; cc < 4; ++cc) h_own[rr][cc] = 0.0f;
    __syncthreads();

    int p = 0;
    for (int t = 0; t < S_LEN; ++t) {
        float xv[8];
#pragma unroll
        for (int rr = 0; rr < 8; ++rr)
            xv[rr] = x[(size_t)(row0 + myrow + rr) * S_LEN + t];

        float acc[3][8][4];
#pragma unroll
        for (int rr = 0; rr < 8; ++rr)
#pragma unroll
            for (int cc = 0; cc < 4; ++cc) {
                acc[0][rr][cc] = fmaf(xv[rr], wih[0][cc], bc[0][cc]);
                acc[1][rr][cc] = fmaf(xv[rr], wih[1][cc], bc[1][cc]);
                acc[2][rr][cc] = bhhn[cc];
            }
        const float* hb = &hbuf[p][0][0];
        for (int k = 0; k < H_DIM; k += 4) {
            float4 hv[8];
#pragma unroll
            for (int rr = 0; rr < 8; ++rr)
                hv[rr] = *(const float4*)(hb + (myrow + rr) * H_DIM + k);
#pragma unroll
            for (int g = 0; g < 3; ++g)
#pragma unroll
                for (int kk = 0; kk < 4; ++kk) {
                    float wrow[4];
#pragma unroll
                    for (int cc = 0; cc < 4; ++cc)
                        wrow[cc] = Whh[(size_t)(g * H_DIM + c0 + cc) * H_DIM + k + kk];
#pragma unroll
                    for (int rr = 0; rr < 8; ++rr) {
                        const float hvv = (&hv[rr].x)[kk];
#pragma unroll
                        for (int cc = 0; cc < 4; ++cc)
                            acc[g][rr][cc] = fmaf(hvv, wrow[cc], acc[g][rr][cc]);
                    }
                }
        }
#pragma unroll
        for (int rr = 0; rr < 8; ++rr) {
            float4 hnew;
#pragma unroll
            for (int cc = 0; cc < 4; ++cc) {
                const float r_  = sigmoid_fast(acc[0][rr][cc]);
                const float z_  = sigmoid_fast(acc[1][rr][cc]);
                const float i_n = fmaf(xv[rr], wih[2][cc], bihn[cc]);
                const float n_  = tanh_fast(fmaf(r_, acc[2][rr][cc], i_n));
                const float hv2 = (1.0f - z_) * n_ + z_ * h_own[rr][cc];
                h_own[rr][cc] = hv2;
                (&hnew.x)[cc] = hv2;
            }
            *(float4*)&hbuf[1 - p][myrow + rr][c0] = hnew;
        }
        __syncthreads();
        p ^= 1;
    }

    const int  pA   = cid;
    const int  pB   = 64 + cid;
    const bool hasB = (cid < 32);
    float accA[8], accB[8];
#pragma unroll
    for (int rr = 0; rr < 8; ++rr) { accA[rr] = 0.0f; accB[rr] = 0.0f; }
    for (int k = 0; k < H_DIM; k += 4) {
        float4 hv[8];
#pragma unroll
        for (int rr = 0; rr < 8; ++rr)
            hv[rr] = *(const float4*)&hbuf[p][myrow + rr][k];
        float wA[4], wB[4];
#pragma unroll
        for (int kk = 0; kk < 4; ++kk) {
            wA[kk] = Wout[(size_t)pA * H_DIM + k + kk];
            wB[kk] = hasB ? Wout[(size_t)pB * H_DIM + k + kk] : 0.0f;
        }
#pragma unroll
        for (int kk = 0; kk < 4; ++kk)
#pragma unroll
            for (int rr = 0; rr < 8; ++rr) {
                const float hvv = (&hv[rr].x)[kk];
                accA[rr] = fmaf(hvv, wA[kk], accA[rr]);
                accB[rr] = fmaf(hvv, wB[kk], accB[rr]);
            }
    }
    const float boA = b_out[pA];
    const float boB = hasB ? b_out[pB] : 0.0f;
#pragma unroll
    for (int rr = 0; rr < 8; ++rr) {
        const size_t orow = (size_t)(row0 + myrow + rr) * P_DIM;
        out[orow + pA] = accA[rr] + boA;
        if (hasB) out[orow + pB] = accB[rr] + boB;
    }
}

extern "C" void kernel_launch(void* const* d_in, const int* in_sizes, int n_in,
                              void* d_out, int out_size, void* d_ws, size_t ws_size,
                              hipStream_t stream) {
    const float* x     = (const float*)d_in[0];
    const float* W_ih  = (const float*)d_in[1];
    const float* W_hh  = (const float*)d_in[2];
    const float* b_ih  = (const float*)d_in[3];
    const float* b_hh  = (const float*)d_in[4];
    const float* W_out = (const float*)d_in[5];
    const float* b_out = (const float*)d_in[6];
    float* out = (float*)d_out;

    const size_t bpack_elems = 8 * 48 * 64 * 8;          // 196608 f16 per matrix
    const size_t wot_elems   = (size_t)H_DIM * P_DIM;    // 24576 fp32
    const size_t ctr_off = bpack_elems * 2 * sizeof(unsigned short) * 2 +
                           wot_elems * sizeof(float);    // 1671168 B (16-aligned)
    const size_t need = ctr_off + sizeof(unsigned int);

    if (ws_size >= need) {
        unsigned short* Bh = (unsigned short*)d_ws;
        unsigned short* Bl = Bh + bpack_elems * 2;
        float* WoT = (float*)(Bl + bpack_elems * 2);
        unsigned int* ctr = (unsigned int*)((char*)d_ws + ctr_off);
        pack_weights<<<G3, H_DIM, 0, stream>>>(W_hh, W_out, Bh, Bl, WoT, ctr);
        gru_mfma<<<B_ROWS / TB, 1024, 0, stream>>>(x, W_ih, b_ih, b_hh,
                                                   Bh, Bl, WoT, b_out, out, ctr);
    } else {
        gru_fallback<<<B_ROWS / TB, 256, 0, stream>>>(x, W_ih, W_hh, b_ih, b_hh,
                                                      W_out, b_out, out);
    }
}

// Round 13
// 3191.702 us; speedup vs baseline: 257.5733x; 1.0353x over previous
//
#include <hip/hip_runtime.h>
#include <math.h>

// Problem constants
#define B_ROWS 8192
#define S_LEN  512
#define H_DIM  256
#define G3     768          // 3*H
#define P_DIM  96
#define TB     32           // batch rows per block

typedef __attribute__((ext_vector_type(8))) _Float16 half8;  // 8 f16 (4 VGPRs)
typedef __attribute__((ext_vector_type(4))) float floatx4;   // MFMA C/D frag

__device__ __forceinline__ float sigmoid_fast(float v) {
    return 1.0f / (1.0f + __expf(-v));
}
__device__ __forceinline__ float tanh_fast(float v) {
    return 1.0f - 2.0f / (__expf(2.0f * v) + 1.0f);
}
__device__ __forceinline__ unsigned short f32_f16(float f) {
    _Float16 h = (_Float16)f;                 // RTN
    return __builtin_bit_cast(unsigned short, h);
}
// Involutive 6-bit lane rotation: spreads scatter dest-lanes across bank groups.
__device__ __forceinline__ int rot3(int l) { return ((l << 3) | (l >> 3)) & 63; }

// -------- One-time weight pack: W_hh -> per-lane MFMA B-fragments (hi/lo fp16).
// h in (-1,1) is sent as SINGLE fp16.  W precision policy (round-11-proven):
//   k=0..223 (kc=0..6): SINGLE fp16 hi only (kc0-5 streamed, kc6 from LDS)
//   k=224..255 (kc=7, registers): split hi+lo (~2^-22 capture)
// B[k][n] = W_hh[n][k].  16x16x32 B-frag: lane holds B[n=lane&15][k=quad*8+j].
// Tile index = (k>>5)*48 + (j>>4); lane = (j&15) | (((k>>3)&3)<<4); short = k&7.
// Also WoT[k][p] = W_out[p][k]; also zeroes the phase-sync counter.
__global__ void pack_weights(const float* __restrict__ W_hh,
                             const float* __restrict__ W_out,
                             unsigned short* __restrict__ Bh,
                             unsigned short* __restrict__ Bl,
                             float* __restrict__ WoT,
                             unsigned int* __restrict__ ctr) {
    const int j = blockIdx.x;    // gate col 0..767
    const int k = threadIdx.x;   // h idx   0..255
    const float wv = W_hh[j * H_DIM + k];
    const unsigned short hi = f32_f16(wv);
    const float hf = (float)__builtin_bit_cast(_Float16, hi);
    const unsigned short lo = f32_f16(wv - hf);
    const int idx = (((k >> 5) * 48 + (j >> 4)) * 64 +
                     ((j & 15) | (((k >> 3) & 3) << 4))) * 8 + (k & 7);
    Bh[idx] = hi;
    Bl[idx] = lo;
    if (j < P_DIM) WoT[k * P_DIM + j] = W_out[j * H_DIM + k];
    if (j == 0 && k == 0) *ctr = 0u;   // d_ws is re-poisoned every launch
}

// LDS layout (84 KiB total; 1 block/CU):
//   [0,       32768)  A-fragments (fp16), double-buffered:
//                     buf*16384 + chunk(kc*2+mt)*1024 + slot*16 + short*2
//                     (slot = rot3'd fragment-lane index)
//   [32768,   36864)  xtile[2][32][16] fp32
//   [36864,   86016)  W cache: 48 tiles x 1 KiB = kc=6 hi (index T=g*16+wv)
#define A_OFF   0
#define X_OFF   32768
#define W_OFF   36864
#define LDS_SZ  86016

// Issue 3 streamed hi-tile loads for one kc (stay in flight until MFMA use).
__device__ __forceinline__ void gissue1(half8 (&BH)[3],
                                        const unsigned short* (&pbh)[3],
                                        int kc) {
#pragma unroll
    for (int g = 0; g < 3; ++g)
        BH[g] = *(const half8*)(pbh[g] + (size_t)kc * 24576);
}

__device__ __forceinline__ void ahread(half8 (&AH)[2], const char* Ac,
                                       int kc, int rl) {
#pragma unroll
    for (int mt = 0; mt < 2; ++mt)
        AH[mt] = *(const half8*)(Ac + (kc * 2 + mt) * 1024 + rl * 16);
}

// Single-precision kc block: 6 MFMAs (hi product only).
__device__ __forceinline__ void kcmfma1(floatx4 (&acc)[3][2],
                                        const half8 (&AH)[2],
                                        const half8 (&BH)[3]) {
#pragma unroll
    for (int g = 0; g < 3; ++g) {
        acc[g][0] = __builtin_amdgcn_mfma_f32_16x16x32_f16(AH[0], BH[g], acc[g][0], 0, 0, 0);
        acc[g][1] = __builtin_amdgcn_mfma_f32_16x16x32_f16(AH[1], BH[g], acc[g][1], 0, 0, 0);
    }
}

// Split-precision kc block: 12 MFMAs (hi+lo) — used for kc7 (registers).
__device__ __forceinline__ void kcmfma2(floatx4 (&acc)[3][2],
                                        const half8 (&AH)[2],
                                        const half8 (&BH)[3],
                                        const half8 (&BL)[3]) {
#pragma unroll
    for (int g = 0; g < 3; ++g) {
        acc[g][0] = __builtin_amdgcn_mfma_f32_16x16x32_f16(AH[0], BH[g], acc[g][0], 0, 0, 0);
        acc[g][1] = __builtin_amdgcn_mfma_f32_16x16x32_f16(AH[1], BH[g], acc[g][1], 0, 0, 0);
        acc[g][0] = __builtin_amdgcn_mfma_f32_16x16x32_f16(AH[0], BL[g], acc[g][0], 0, 0, 0);
        acc[g][1] = __builtin_amdgcn_mfma_f32_16x16x32_f16(AH[1], BL[g], acc[g][1], 0, 0, 0);
    }
}

// Main persistent GRU kernel (round 13 = round 12 + explicit register budget).
// Allocator heuristic (fitted to 7 data points): targets 2 blocks/CU worth of
// occupancy regardless of launch_bounds min -> a 1024-thread block gets only
// 64 VGPRs/wave and spills (r12: WRITE_SIZE 20.7 MB scratch, VALUBusy 62%).
// amdgpu_waves_per_eu(4,4) overrides: exactly 4 waves/EU -> 128-reg unified
// budget/wave, fitting the ~88-reg live set (acc 24 AGPR + ~64 arch) with
// zero spill.  16 waves from ONE block keep the proven 1-block heartbeat.
// grid = 256 (1 block/CU), block = 1024 (16 waves).
__global__ __launch_bounds__(1024)
__attribute__((amdgpu_waves_per_eu(4, 4)))
void gru_mfma(const float* __restrict__ x,
              const float* __restrict__ W_ih,
              const float* __restrict__ b_ih,
              const float* __restrict__ b_hh,
              const unsigned short* __restrict__ Bh,
              const unsigned short* __restrict__ Bl,
              const float* __restrict__ WoT,   // [256][96]
              const float* __restrict__ b_out,
              float* __restrict__ out,
              unsigned int* __restrict__ ctr) {
    __shared__ __align__(16) char smem[LDS_SZ];

    const int tid  = threadIdx.x;
    const int wv   = tid >> 6;     // wave 0..15; owns gate-cols g*256 + wv*16 + c
    const int lane = tid & 63;
    const int q    = lane >> 4;    // quad
    const int c    = lane & 15;
    const int row0 = blockIdx.x * TB;

    // Per-thread gate params; col = 256*g + 16*wv + c
    float wih[3], bcc[2], bihn, bhhn;
#pragma unroll
    for (int g = 0; g < 3; ++g) {
        const int col = g * H_DIM + wv * 16 + c;
        wih[g] = W_ih[col];
        if (g < 2) {
            bcc[g] = b_ih[col] + b_hh[col];
        } else {
            bihn = b_ih[col];
            bhhn = b_hh[col];
        }
    }

    // Streamed-tile base pointers (per wave/lane); tile index T = g*16 + wv.
    const unsigned short* pbh[3];
#pragma unroll
    for (int g = 0; g < 3; ++g)
        pbh[g] = Bh + (size_t)(g * 16 + wv) * 512 + lane * 8;

    // Register-resident weight tiles: kc=7 hi+lo.  (24 VGPRs)
    half8 r7h[3], r7l[3];
#pragma unroll
    for (int g = 0; g < 3; ++g) {
        const size_t toff = (size_t)(g * 16 + wv) * 512 + lane * 8;
        r7h[g] = *(const half8*)(Bh + toff + 7 * 24576);
        r7l[g] = *(const half8*)(Bl + toff + 7 * 24576);
    }

    // LDS weight cache staging: 48 tiles = kc=6 hi only.
    for (int i = tid; i < 48 * 64; i += 1024) {
        const int slot = i >> 6, l16 = i & 63;
        const unsigned short* src = Bh + (size_t)(288 + slot) * 512 + l16 * 8;
        *(uint4*)(smem + W_OFF + slot * 1024 + l16 * 16) = *(const uint4*)src;
    }

    // Zero both A-frag buffers (h0 = 0) and stage x for t=0..15.
    for (int i = tid; i < 8192; i += 1024) ((int*)(smem + A_OFF))[i] = 0;
    float* xt = (float*)(smem + X_OFF);
    if (tid < 512) {
        const int r = tid >> 4, t2 = tid & 15;
        xt[r * 16 + t2] = x[(size_t)(row0 + r) * S_LEN + t2];
    }
    __syncthreads();

    // h_old in C-frag layout: element (mt,reg) = h[4q+reg+16mt][16wv+c]
    float h_own[2][4];
#pragma unroll
    for (int mt = 0; mt < 2; ++mt)
#pragma unroll
        for (int r = 0; r < 4; ++r) h_own[mt][r] = 0.0f;

    const int rl = rot3(lane);

    // Loop-invariant precompute.
    const int hchunk = (wv >> 1) * 2;           // A-chunk pair this wave scatters
    const int cg     = 2 * (wv & 1) + (c >> 3); // col-group within chunk
    int soff[4];                                // [r] -> rot3(d)*16 + (c&7)*2
#pragma unroll
    for (int r = 0; r < 4; ++r) {
        const int d = (q * 4 + r) | (cg << 4);
        soff[r] = rot3(d) * 16 + (c & 7) * 2;
    }
    int xbase[2][4];                            // [mt][r] -> (q*4+r+16mt)*16
#pragma unroll
    for (int mt = 0; mt < 2; ++mt)
#pragma unroll
        for (int r = 0; r < 4; ++r)
            xbase[mt][r] = (q * 4 + r + 16 * mt) * 16;
    const char* w6base[3];                      // kc6 hi tile, T = g*16+wv
#pragma unroll
    for (int g = 0; g < 3; ++g)
        w6base[g] = smem + W_OFF + (g * 16 + wv) * 1024 + lane * 16;

    // Pipeline buffers (static names only — rule: no runtime indexing).
    half8 b0h[3], b1h[3];
    half8 ahA[2], ahB[2];

    // Prologue: kc=0 of step 0 in flight before the loop.
    gissue1(b0h, pbh, 0);

#pragma unroll 1
    for (int t = 0; t < S_LEN; ++t) {
        // Defeat LICM of the (t-invariant) streamed loads.
#pragma unroll
        for (int g = 0; g < 3; ++g)
            asm volatile("" : "+v"(pbh[g]));

        const int cur = t & 1, nxt = cur ^ 1;
        const char* Ac = smem + A_OFF + cur * 16384;

        ahread(ahA, Ac, 0, rl);            // A-frags for kc=0
        gissue1(b1h, pbh, 1);              // kc=1 stream in flight

        // x for my 8 rows (LDS broadcast); xidx is wave-uniform per step.
        const int xidx = ((t >> 4) & 1) * 512 + (t & 15);
        float xr[2][4];
#pragma unroll
        for (int mt = 0; mt < 2; ++mt)
#pragma unroll
            for (int r = 0; r < 4; ++r)
                xr[mt][r] = xt[xbase[mt][r] + xidx];

        // C frags [gate][mt]; fold x-side pre-activation + bias into init.
        floatx4 acc[3][2];
#pragma unroll
        for (int mt = 0; mt < 2; ++mt)
#pragma unroll
            for (int r = 0; r < 4; ++r) {
                acc[0][mt][r] = fmaf(xr[mt][r], wih[0], bcc[0]);
                acc[1][mt][r] = fmaf(xr[mt][r], wih[1], bcc[1]);
                acc[2][mt][r] = bhhn;
            }

        // ---- Pipelined kc ladder (single-fp16 stream): consume kc,
        //      stream kc+1, read A(kc+1) ----
        ahread(ahB, Ac, 1, rl);
        kcmfma1(acc, ahA, b0h);                           // kc0
        gissue1(b0h, pbh, 2);
        ahread(ahA, Ac, 2, rl);
        kcmfma1(acc, ahB, b1h);                           // kc1
        gissue1(b1h, pbh, 3);
        ahread(ahB, Ac, 3, rl);
        kcmfma1(acc, ahA, b0h);                           // kc2
        gissue1(b0h, pbh, 4);
        ahread(ahA, Ac, 4, rl);
        kcmfma1(acc, ahB, b1h);                           // kc3
        gissue1(b1h, pbh, 5);
        ahread(ahB, Ac, 5, rl);
        kcmfma1(acc, ahA, b0h);                           // kc4
        ahread(ahA, Ac, 6, rl);
        kcmfma1(acc, ahB, b1h);                           // kc5

        // ---- kc6: hi from the LDS cache (single precision) ----
        {
            half8 w6h[3];
#pragma unroll
            for (int g = 0; g < 3; ++g)
                w6h[g] = *(const half8*)(w6base[g]);
            ahread(ahB, Ac, 7, rl);
            kcmfma1(acc, ahA, w6h);                       // kc6
        }

        // Prefetch next step's kc0 while kc7 + gates + barrier run.
        gissue1(b0h, pbh, 0);
        kcmfma2(acc, ahB, r7h, r7l);                      // kc7 (split)

        // Gates + h update (in-register); scatter next A-frags (rot3-swizzled).
        char* Anx = smem + A_OFF + nxt * 16384;
#pragma unroll
        for (int mt = 0; mt < 2; ++mt) {
            char* ch = Anx + (hchunk + mt) * 1024;        // chunk kc = wv>>1
#pragma unroll
            for (int r = 0; r < 4; ++r) {
                const float rr  = sigmoid_fast(acc[0][mt][r]);
                const float zz  = sigmoid_fast(acc[1][mt][r]);
                const float inn = fmaf(xr[mt][r], wih[2], bihn);
                const float nn  = tanh_fast(fmaf(rr, acc[2][mt][r], inn));
                const float hv  = (1.0f - zz) * nn + zz * h_own[mt][r];
                h_own[mt][r] = hv;
                *(unsigned short*)(ch + soff[r]) = f32_f16(hv);
            }
        }

        // Re-stage x for the next 16 steps (into the idle x buffer).
        const bool tick = ((t & 15) == 15) && (t != S_LEN - 1);
        if (tick && tid < 512) {
            const int r = tid >> 4, t2 = tid & 15;
            xt[((((t + 1) >> 4) & 1) * 32 + r) * 16 + t2] =
                x[(size_t)(row0 + r) * S_LEN + (t + 1) + t2];
        }
        __syncthreads();   // single barrier: next A-frags + x tile visible

        // Phase-alignment heartbeat every 16 steps: keeps all 256 blocks'
        // weight streams in phase so the per-XCD L2 working set stays hot.
        // Safe: grid == 256 == CU count, all blocks co-resident.
        if (tick) {
            if (tid == 0) {
                const unsigned int tgt = 256u * (unsigned)((t >> 4) + 1);
                atomicAdd(ctr, 1u);
                for (int spin = 0; spin < (1 << 17); ++spin) {
                    if (__hip_atomic_load(ctr, __ATOMIC_RELAXED,
                                          __HIP_MEMORY_SCOPE_AGENT) >= tgt) break;
                    __builtin_amdgcn_s_sleep(4);
                }
            }
            __syncthreads();
        }
    }

    // -------- Epilogue: dump final h (fp32, from registers) and project.
    float* hfin = (float*)(smem);   // reuse A region: [32][256] = 32 KiB
#pragma unroll
    for (int mt = 0; mt < 2; ++mt)
#pragma unroll
        for (int r = 0; r < 4; ++r) {
            const int m = q * 4 + r + 16 * mt;
            const int k = wv * 16 + c;
            hfin[m * H_DIM + k] = h_own[mt][r];
        }
    __syncthreads();

    if (tid < 256) {
        const int cid   = tid & 63;
        const int rid   = tid >> 6;
        const int myrow = rid * 8;
        const int pA    = cid;
        const int pB    = 64 + cid;
        const bool hasB = (cid < 32);
        float accA[8], accB[8];
#pragma unroll
        for (int rr = 0; rr < 8; ++rr) { accA[rr] = 0.0f; accB[rr] = 0.0f; }

        for (int k = 0; k < H_DIM; k += 4) {
            float4 hv[8];
#pragma unroll
            for (int rr = 0; rr < 8; ++rr)
                hv[rr] = *(const float4*)&hfin[(myrow + rr) * H_DIM + k];
            float wA[4], wB[4];
#pragma unroll
            for (int kk = 0; kk < 4; ++kk) {
                wA[kk] = WoT[(size_t)(k + kk) * P_DIM + pA];
                wB[kk] = hasB ? WoT[(size_t)(k + kk) * P_DIM + pB] : 0.0f;
            }
#pragma unroll
            for (int kk = 0; kk < 4; ++kk)
#pragma unroll
                for (int rr = 0; rr < 8; ++rr) {
                    const float hvv = (&hv[rr].x)[kk];
                    accA[rr] = fmaf(hvv, wA[kk], accA[rr]);
                    accB[rr] = fmaf(hvv, wB[kk], accB[rr]);
                }
        }
        const float boA = b_out[pA];
        const float boB = hasB ? b_out[pB] : 0.0f;
#pragma unroll
        for (int rr = 0; rr < 8; ++rr) {
            const size_t orow = (size_t)(row0 + myrow + rr) * P_DIM;
            out[orow + pA] = accA[rr] + boA;
            if (hasB) out[orow + pB] = accB[rr] + boB;
        }
    }
}

// -------- fp32 fallback — used only if ws_size is too small.
__global__ __launch_bounds__(256, 1)
void gru_fallback(const float* __restrict__ x,
                  const float* __restrict__ W_ih,
                  const float* __restrict__ Whh,
                  const float* __restrict__ b_ih,
                  const float* __restrict__ b_hh,
                  const float* __restrict__ Wout,
                  const float* __restrict__ b_out,
                  float* __restrict__ out) {
    __shared__ float hbuf[2][TB][H_DIM];

    const int tid   = threadIdx.x;
    const int cid   = tid & 63;
    const int rid   = tid >> 6;
    const int row0  = blockIdx.x * TB;
    const int myrow = rid * 8;
    const int c0    = cid * 4;

    float wih[3][4], bc[2][4], bihn[4], bhhn[4];
#pragma unroll
    for (int cc = 0; cc < 4; ++cc) {
        const int j = c0 + cc;
        wih[0][cc] = W_ih[j];
        wih[1][cc] = W_ih[H_DIM + j];
        wih[2][cc] = W_ih[2 * H_DIM + j];
        bc[0][cc]  = b_ih[j] + b_hh[j];
        bc[1][cc]  = b_ih[H_DIM + j] + b_hh[H_DIM + j];
        bihn[cc]   = b_ih[2 * H_DIM + j];
        bhhn[cc]   = b_hh[2 * H_DIM + j];
    }
    for (int i = tid; i < TB * H_DIM; i += 256) (&hbuf[0][0][0])[i] = 0.0f;
    float h_own[8][4];
#pragma unroll
    for (int rr = 0; rr < 8; ++rr)
#pragma unroll
        for (int cc = 0; cc < 4; ++cc) h_own[rr][cc] = 0.0f;
    __syncthreads();

    int p = 0;
    for (int t = 0; t < S_LEN; ++t) {
        float xv[8];
#pragma unroll
        for (int rr = 0; rr < 8; ++rr)
            xv[rr] = x[(size_t)(row0 + myrow + rr) * S_LEN + t];

        float acc[3][8][4];
#pragma unroll
        for (int rr = 0; rr < 8; ++rr)
#pragma unroll
            for (int cc = 0; cc < 4; ++cc) {
                acc[0][rr][cc] = fmaf(xv[rr], wih[0][cc], bc[0][cc]);
                acc[1][rr][cc] = fmaf(xv[rr], wih[1][cc], bc[1][cc]);
                acc[2][rr][cc] = bhhn[cc];
            }
        const float* hb = &hbuf[p][0][0];
        for (int k = 0; k < H_DIM; k += 4) {
            float4 hv[8];
#pragma unroll
            for (int rr = 0; rr < 8; ++rr)
                hv[rr] = *(const float4*)(hb + (myrow + rr) * H_DIM + k);
#pragma unroll
            for (int g = 0; g < 3; ++g)
#pragma unroll
                for (int kk = 0; kk < 4; ++kk) {
                    float wrow[4];
#pragma unroll
                    for (int cc = 0; cc < 4; ++cc)
                        wrow[cc] = Whh[(size_t)(g * H_DIM + c0 + cc) * H_DIM + k + kk];
#pragma unroll
                    for (int rr = 0; rr < 8; ++rr) {
                        const float hvv = (&hv[rr].x)[kk];
#pragma unroll
                        for (int cc = 0; cc < 4; ++cc)
                            acc[g][rr][cc] = fmaf(hvv, wrow[cc], acc[g][rr][cc]);
                    }
                }
        }
#pragma unroll
        for (int rr = 0; rr < 8; ++rr) {
            float4 hnew;
#pragma unroll
            for (int cc = 0; cc < 4; ++cc) {
                const float r_  = sigmoid_fast(acc[0][rr][cc]);
                const float z_  = sigmoid_fast(acc[1][rr][cc]);
                const float i_n = fmaf(xv[rr], wih[2][cc], bihn[cc]);
                const float n_  = tanh_fast(fmaf(r_, acc[2][rr][cc], i_n));
                const float hv2 = (1.0f - z_) * n_ + z_ * h_own[rr][cc];
                h_own[rr][cc] = hv2;
                (&hnew.x)[cc] = hv2;
            }
            *(float4*)&hbuf[1 - p][myrow + rr][c0] = hnew;
        }
        __syncthreads();
        p ^= 1;
    }

    const int  pA   = cid;
    const int  pB   = 64 + cid;
    const bool hasB = (cid < 32);
    float accA[8], accB[8];
#pragma unroll
    for (int rr = 0; rr < 8; ++rr) { accA[rr] = 0.0f; accB[rr] = 0.0f; }
    for (int k = 0; k < H_DIM; k += 4) {
        float4 hv[8];
#pragma unroll
        for (int rr = 0; rr < 8; ++rr)
            hv[rr] = *(const float4*)&hbuf[p][myrow + rr][k];
        float wA[4], wB[4];
#pragma unroll
        for (int kk = 0; kk < 4; ++kk) {
            wA[kk] = Wout[(size_t)pA * H_DIM + k + kk];
            wB[kk] = hasB ? Wout[(size_t)pB * H_DIM + k + kk] : 0.0f;
        }
#pragma unroll
        for (int kk = 0; kk < 4; ++kk)
#pragma unroll
            for (int rr = 0; rr < 8; ++rr) {
                const float hvv = (&hv[rr].x)[kk];
                accA[rr] = fmaf(hvv, wA[kk], accA[rr]);
                accB[rr] = fmaf(hvv, wB[kk], accB[rr]);
            }
    }
    const float boA = b_out[pA];
    const float boB = hasB ? b_out[pB] : 0.0f;
#pragma unroll
    for (int rr = 0; rr < 8; ++rr) {
        const size_t orow = (size_t)(row0 + myrow + rr) * P_DIM;
        out[orow + pA] = accA[rr] + boA;
        if (hasB) out[orow + pB] = accB[rr] + boB;
    }
}

extern "C" void kernel_launch(void* const* d_in, const int* in_sizes, int n_in,
                              void* d_out, int out_size, void* d_ws, size_t ws_size,
                              hipStream_t stream) {
    const float* x     = (const float*)d_in[0];
    const float* W_ih  = (const float*)d_in[1];
    const float* W_hh  = (const float*)d_in[2];
    const float* b_ih  = (const float*)d_in[3];
    const float* b_hh  = (const float*)d_in[4];
    const float* W_out = (const float*)d_in[5];
    const float* b_out = (const float*)d_in[6];
    float* out = (float*)d_out;

    const size_t bpack_elems = 8 * 48 * 64 * 8;          // 196608 f16 per matrix
    const size_t wot_elems   = (size_t)H_DIM * P_DIM;    // 24576 fp32
    const size_t ctr_off = bpack_elems * 2 * sizeof(unsigned short) * 2 +
                           wot_elems * sizeof(float);    // 1671168 B (16-aligned)
    const size_t need = ctr_off + sizeof(unsigned int);

    if (ws_size >= need) {
        unsigned short* Bh = (unsigned short*)d_ws;
        unsigned short* Bl = Bh + bpack_elems * 2;
        float* WoT = (float*)(Bl + bpack_elems * 2);
        unsigned int* ctr = (unsigned int*)((char*)d_ws + ctr_off);
        pack_weights<<<G3, H_DIM, 0, stream>>>(W_hh, W_out, Bh, Bl, WoT, ctr);
        gru_mfma<<<B_ROWS / TB, 1024, 0, stream>>>(x, W_ih, b_ih, b_hh,
                                                   Bh, Bl, WoT, b_out, out, ctr);
    } else {
        gru_fallback<<<B_ROWS / TB, 256, 0, stream>>>(x, W_ih, W_hh, b_ih, b_hh,
                                                      W_out, b_out, out);
    }
}